// Round 6
// baseline (372.597 us; speedup 1.0000x reference)
//
#include <hip/hip_runtime.h>
#include <cstdint>
#include <cstddef>

typedef __bf16 bf16;
typedef __bf16 bf16x8 __attribute__((ext_vector_type(8)));
typedef __bf16 bf16x4 __attribute__((ext_vector_type(4)));
typedef float f32x4 __attribute__((ext_vector_type(4)));
typedef float f32x16 __attribute__((ext_vector_type(16)));

#define TOKENS 4096   // B*T
#define TSEQ   2048
#define NHEADS 16
#define HDIM   64
#define CDIM   1024

// ---- async global->LDS, 16B per lane ----
typedef __attribute__((address_space(3))) unsigned int lds_uint;
typedef __attribute__((address_space(1))) const unsigned int g_uint;
__device__ __forceinline__ void glds16(const bf16* g, bf16* l) {
  __builtin_amdgcn_global_load_lds((g_uint*)g, (lds_uint*)l, 16, 0, 0);
}

// fast GELU: x*sigmoid(1.5957691x + 0.0713548x^3); max dev from erf-GELU ~3e-4
__device__ __forceinline__ float gelu_f(float v) {
  float g2 = v * (1.5957691216f + 0.0713548163f * v * v);
  return v / (1.0f + __expf(-g2));
}

// ------------------------------------------------------------------
// Input dtype detection (insurance; fp32 -> flag 0).
// ------------------------------------------------------------------
#define NBUF 17
struct DetectArgs { const void* p[NBUF]; int n[NBUF]; };

__global__ __launch_bounds__(256) void detect_kernel(DetectArgs a, int* __restrict__ flags) {
  __shared__ int s_nz, s_bl;
  if (threadIdx.x == 0) { s_nz = 0; s_bl = 0; }
  __syncthreads();
  int i = blockIdx.x;
  const unsigned int* w = (const unsigned int*)a.p[i];
  int nwords = a.n[i] / 2; if (nwords > 2048) nwords = 2048;
  int nz = 0, bl = 0;
  for (int j = threadIdx.x; j < nwords; j += 256) {
    unsigned int v = w[j];
    if (v != 0u) {
      nz++;
      unsigned int e = (v >> 7) & 0xFFu;
      if (e >= 100u && e <= 140u) bl++;
    }
  }
  atomicAdd(&s_nz, nz);
  atomicAdd(&s_bl, bl);
  __syncthreads();
  if (threadIdx.x == 0) flags[i] = (2 * s_bl >= s_nz) ? 1 : 0;
}

__device__ __forceinline__ float ld_any(const void* p, size_t idx, bool isb) {
  return isb ? (float)((const bf16*)p)[idx] : ((const float*)p)[idx];
}

// ------------------------------------------------------------------
// LayerNorm stats (rows of 1024, 256 threads): returns mu, rstd
// ------------------------------------------------------------------
__device__ __forceinline__ void ln_stats(float s, float s2, int tid, float& mu, float& rstd) {
#pragma unroll
  for (int off = 32; off; off >>= 1) {
    s  += __shfl_down(s, off);
    s2 += __shfl_down(s2, off);
  }
  __shared__ float red[8];
  int w = tid >> 6;
  if ((tid & 63) == 0) { red[w] = s; red[4 + w] = s2; }
  __syncthreads();
  if (tid == 0) {
    red[0] = red[0] + red[1] + red[2] + red[3];
    red[4] = red[4] + red[5] + red[6] + red[7];
  }
  __syncthreads();
  mu = red[0] * (1.0f / CDIM);
  float var = fmaxf(red[4] * (1.0f / CDIM) - mu * mu, 0.f);
  rstd = rsqrtf(var + 1e-5f);
}

__global__ __launch_bounds__(256) void ln_f32(const float* __restrict__ x,
                                              const bf16* __restrict__ g,
                                              const bf16* __restrict__ b,
                                              bf16* __restrict__ y) {
  int row = blockIdx.x, tid = threadIdx.x;
  float v[4]; float s = 0.f, s2 = 0.f;
#pragma unroll
  for (int i = 0; i < 4; i++) {
    float f = x[(size_t)row * CDIM + tid * 4 + i];
    v[i] = f; s += f; s2 += f * f;
  }
  float mu, rstd;
  ln_stats(s, s2, tid, mu, rstd);
  bf16* yr = y + (size_t)row * CDIM;
#pragma unroll
  for (int i = 0; i < 4; i++) {
    int c = tid * 4 + i;
    yr[c] = (bf16)((v[i] - mu) * rstd * (float)g[c] + (float)b[c]);
  }
}

// ------------------------------------------------------------------
// Mega preprocessing kernel (ONE launch): 6 weight transposes (+convert),
// 10 small-vector converts, LN1 over 4096 rows.
// ------------------------------------------------------------------
struct MegaArgs {
  const void* w_in[6]; bf16* w_out[6]; int wK[6], wN[6], wflag[6];
  const void* vp[10]; bf16* vd[10]; int vn[10], vfi[10];
  const void* x; const void* graw; const void* braw; bf16* y;
};

__global__ __launch_bounds__(256) void mega_pre(MegaArgs a, const int* __restrict__ flags) {
  int bid = blockIdx.x;
  int tx = threadIdx.x, ty = threadIdx.y;          // blockDim (64,4)
  int tid = tx + ty * 64;
  if (bid < 3072) {
    __shared__ bf16 tile[64][65];
    int mi, start;
    if (bid < 1024)      { mi = bid >> 8; start = mi << 8; }
    else if (bid < 2048) { mi = 4; start = 1024; }
    else                 { mi = 5; start = 2048; }
    int tb = bid - start;
    int nT = a.wN[mi] >> 6;
    int kb = (tb / nT) * 64, nb = (tb % nT) * 64;
    int K = a.wK[mi], N = a.wN[mi];
    bool isb = flags[a.wflag[mi]] != 0;
    const void* in = a.w_in[mi]; bf16* out = a.w_out[mi];
    for (int i = ty; i < 64; i += 4)
      tile[i][tx] = (bf16)ld_any(in, (size_t)(kb + i) * N + nb + tx, isb);
    __syncthreads();
    for (int i = ty; i < 64; i += 4)
      out[(size_t)(nb + i) * K + kb + tx] = tile[tx][i];
  } else if (bid == 3072) {
    for (int i = 0; i < 10; i++) {
      bool isb = flags[a.vfi[i]] != 0;
      const void* in = a.vp[i]; bf16* out = a.vd[i]; int n = a.vn[i];
      for (int j = tid; j < n; j += 256)
        out[j] = (bf16)ld_any(in, j, isb);
    }
  } else {
    int row = bid - 3073;
    bool isb  = flags[0] != 0;
    bool gisb = flags[1] != 0;
    bool bisb = flags[2] != 0;
    float v[4]; float s = 0.f, s2 = 0.f;
#pragma unroll
    for (int i = 0; i < 4; i++) {
      float f = ld_any(a.x, (size_t)row * CDIM + tid * 4 + i, isb);
      v[i] = f; s += f; s2 += f * f;
    }
    float mu, rstd;
    ln_stats(s, s2, tid, mu, rstd);
    bf16* yr = a.y + (size_t)row * CDIM;
#pragma unroll
    for (int i = 0; i < 4; i++) {
      int c = tid * 4 + i;
      float gv = ld_any(a.graw, c, gisb);
      float bv = ld_any(a.braw, c, bisb);
      yr[c] = (bf16)((v[i] - mu) * rstd * gv + bv);
    }
  }
}

// ------------------------------------------------------------------
// Legacy GEMM core (BM<=128): single-buffer 2-barrier. Kept for Wo.
// ------------------------------------------------------------------
template <int BM, int BN>
__device__ __forceinline__ void gemm_core(const bf16* __restrict__ A,
                                          const bf16* __restrict__ Bt,
                                          int K, int m0, int n0,
                                          bf16* As, bf16* Bs,
                                          f32x4 (&acc)[BM / 32][BN / 32]) {
  constexpr int SI = BM / 32, SJ = BN / 32;
  int t = threadIdx.x;
  int wave = t >> 6, lane = t & 63, quad = lane >> 4, l16 = lane & 15;
  int wm = (wave & 1) * (BM / 2), wn = (wave >> 1) * (BN / 2);
  int srow = t >> 2, sc = t & 3;
  int swz = (srow >> 1) & 3;
  const bf16* ga[BM / 64];
  const bf16* gb[BN / 64];
#pragma unroll
  for (int h = 0; h < BM / 64; h++)
    ga[h] = A + (size_t)(m0 + h * 64 + srow) * K + (sc ^ swz) * 8;
#pragma unroll
  for (int h = 0; h < BN / 64; h++)
    gb[h] = Bt + (size_t)(n0 + h * 64 + srow) * K + (sc ^ swz) * 8;

  for (int k0 = 0; k0 < K; k0 += 64) {
#pragma unroll
    for (int q = 0; q < 2; q++) {
#pragma unroll
      for (int h = 0; h < BM / 64; h++)
        glds16(ga[h] + k0 + q * 32, As + q * (BM * 32) + h * 2048 + srow * 32 + sc * 8);
#pragma unroll
      for (int h = 0; h < BN / 64; h++)
        glds16(gb[h] + k0 + q * 32, Bs + q * (BN * 32) + h * 2048 + srow * 32 + sc * 8);
    }
    __syncthreads();
#pragma unroll
    for (int q = 0; q < 2; q++) {
      bf16x8 af[SI], bfr[SJ];
#pragma unroll
      for (int i = 0; i < SI; i++) {
        int m = wm + i * 16 + l16;
        af[i] = *(const bf16x8*)&As[q * (BM * 32) + m * 32 + ((quad ^ ((m >> 1) & 3)) * 8)];
      }
#pragma unroll
      for (int j = 0; j < SJ; j++) {
        int n = wn + j * 16 + l16;
        bfr[j] = *(const bf16x8*)&Bs[q * (BN * 32) + n * 32 + ((quad ^ ((n >> 1) & 3)) * 8)];
      }
#pragma unroll
      for (int i = 0; i < SI; i++)
#pragma unroll
        for (int j = 0; j < SJ; j++)
          acc[i][j] = __builtin_amdgcn_mfma_f32_16x16x32_bf16(af[i], bfr[j], acc[i][j], 0, 0, 0);
    }
    __syncthreads();
  }
}

#define EPI_NONE 0
#define EPI_RES  1
#define EPI_GELU 2

template <int BM, int BN, int EPI, typename OutT, typename ResT>
__global__ __launch_bounds__(256) void gemm128(const bf16* __restrict__ A,
                                               const bf16* __restrict__ Bt,
                                               const bf16* __restrict__ bias,
                                               const ResT* __restrict__ res,
                                               OutT* __restrict__ C,
                                               int N, int K) {
  __shared__ alignas(16) bf16 As[2 * BM * 32];
  __shared__ alignas(16) bf16 Bs[2 * BN * 32];
  int m0 = blockIdx.y * BM, n0 = blockIdx.x * BN;
  f32x4 acc[BM / 32][BN / 32] = {};
  gemm_core<BM, BN>(A, Bt, K, m0, n0, As, Bs, acc);

  int t = threadIdx.x, wave = t >> 6, lane = t & 63, quad = lane >> 4, l16 = lane & 15;
  int wm = (wave & 1) * (BM / 2), wn = (wave >> 1) * (BN / 2);
#pragma unroll
  for (int i = 0; i < BM / 32; i++)
#pragma unroll
    for (int j = 0; j < BN / 32; j++) {
      int n = n0 + wn + j * 16 + l16;
      float bv = (float)bias[n];
#pragma unroll
      for (int r = 0; r < 4; r++) {
        int m = m0 + wm + i * 16 + quad * 4 + r;
        float v = acc[i][j][r] + bv;
        if (EPI == EPI_GELU)      v = gelu_f(v);
        else if (EPI == EPI_RES)  v += (float)res[(size_t)m * N + n];
        C[(size_t)m * N + n] = (OutT)v;
      }
    }
}

// ------------------------------------------------------------------
// 256x256 8-phase GEMM core (T2+T3+T4+T5): 512 threads = 8 waves (2Mx4N),
// per-wave 128x64 output, BK=64, 128 KiB double-buffered LDS, counted
// vmcnt(6) only at phases 4/8. lda/ldb allow K-sliced operands.
// ------------------------------------------------------------------
__device__ __forceinline__ void gemm256_core(const bf16* __restrict__ A,
                                             const bf16* __restrict__ Bt,
                                             int K, int lda, int ldb, int m0, int n0,
                                             bf16* sm, f32x4 (&acc)[8][4]) {
  const int NT = K >> 6;
  const int t = threadIdx.x;
  const int lane = t & 63, quad = lane >> 4, l16 = lane & 15;
  const int wave = t >> 6;
  const int wm = (wave & 1) * 128, wn = (wave >> 1) * 64;
  const int srow = t >> 2, sc = t & 3;
  const int swz = (srow >> 1) & 3;
  const int rA = (srow & 63) + ((srow >> 6) << 7);   // A-u1 row; u2 = +64
  const bf16* gA = A + (size_t)(m0 + rA) * lda + ((sc ^ swz) << 3);
  const bf16* gB = Bt + (size_t)(n0 + srow) * ldb + ((sc ^ swz) << 3);
  const int ldsA = rA * 32 + sc * 8;
  const int ldsB = srow * 32 + sc * 8;

  auto stA = [&](int tile, int u) {   // u: 0 = rows [0,64)+[128,192), 1 = +64
    if (tile >= NT) return;
    const bf16* g = gA + (size_t)(u << 6) * lda + (tile << 6);
    bf16* l = sm + ((tile & 1) << 15) + ldsA + (u << 11);
    glds16(g, l);
    glds16(g + 32, l + 8192);
  };
  auto stB = [&](int tile, int h) {   // h: 0 = rows [0,128), 1 = [128,256)
    if (tile >= NT) return;
    const bf16* g = gB + (size_t)(h << 7) * ldb + (tile << 6);
    bf16* l = sm + ((tile & 1) << 15) + 16384 + ldsB + (h << 12);
    glds16(g, l);
    glds16(g + 32, l + 8192);
  };

  // prologue: mimic steady-state (j-1)P2..P8, end with vmcnt(6)+barrier
  stB(0, 0); stB(0, 1); stA(0, 0); stA(0, 1);
  stB(1, 0); stB(1, 1); stA(1, 0);
  asm volatile("s_waitcnt vmcnt(6)" ::: "memory");
  __builtin_amdgcn_s_barrier();
  asm volatile("" ::: "memory");

  bf16x8 bfr[2][4];

#define LDB256(buf)                                                        \
  _Pragma("unroll") for (int q = 0; q < 2; q++)                            \
  _Pragma("unroll") for (int j = 0; j < 4; j++) {                          \
    int nl = wn + j * 16 + l16;                                            \
    bfr[q][j] = *(const bf16x8*)&sm[((buf) << 15) + 16384 + q * 8192 +     \
                                    nl * 32 + ((quad ^ ((nl >> 1) & 3)) << 3)]; \
  }

#define PHASE256(buf, P, STAGE, EXTRAWAIT)                                 \
  {                                                                        \
    bf16x8 af[2][2];                                                       \
    _Pragma("unroll") for (int q = 0; q < 2; q++)                          \
    _Pragma("unroll") for (int i2 = 0; i2 < 2; i2++) {                     \
      int ml = wm + (P) * 32 + i2 * 16 + l16;                              \
      af[q][i2] = *(const bf16x8*)&sm[((buf) << 15) + q * 8192 + ml * 32 + \
                                      ((quad ^ ((ml >> 1) & 3)) << 3)];    \
    }                                                                      \
    if ((P) == 0) { LDB256(buf); }                                         \
    STAGE;                                                                 \
    asm volatile("" ::: "memory");                                         \
    __builtin_amdgcn_s_barrier();                                          \
    asm volatile("s_waitcnt lgkmcnt(0)" ::: "memory");                     \
    __builtin_amdgcn_s_setprio(1);                                         \
    _Pragma("unroll") for (int q = 0; q < 2; q++)                          \
    _Pragma("unroll") for (int i2 = 0; i2 < 2; i2++)                       \
    _Pragma("unroll") for (int j = 0; j < 4; j++)                          \
      acc[(P) * 2 + i2][j] = __builtin_amdgcn_mfma_f32_16x16x32_bf16(      \
          af[q][i2], bfr[q][j], acc[(P) * 2 + i2][j], 0, 0, 0);            \
    __builtin_amdgcn_s_setprio(0);                                         \
    asm volatile("" ::: "memory");                                         \
    EXTRAWAIT;                                                             \
    __builtin_amdgcn_s_barrier();                                          \
    asm volatile("" ::: "memory");                                         \
  }

  for (int t0 = 0; t0 < NT; t0 += 2) {
    const int t1 = t0 + 1;
    PHASE256(0, 0, stA(t1, 1), (void)0);
    PHASE256(0, 1, stB(t0 + 2, 0), (void)0);
    PHASE256(0, 2, stB(t0 + 2, 1), (void)0);
    PHASE256(0, 3, stA(t0 + 2, 0),
             asm volatile("s_waitcnt vmcnt(6)" ::: "memory"));
    PHASE256(1, 0, stA(t0 + 2, 1), (void)0);
    PHASE256(1, 1, stB(t1 + 2, 0), (void)0);
    PHASE256(1, 2, stB(t1 + 2, 1), (void)0);
    PHASE256(1, 3, stA(t1 + 2, 0),
             asm volatile("s_waitcnt vmcnt(6)" ::: "memory"));
  }
#undef PHASE256
#undef LDB256
}

__device__ __forceinline__ void xcd_swizzle(int& bx, int& by) {
  int gx = gridDim.x;
  int nwg = gx * gridDim.y;
  int bid = blockIdx.x + blockIdx.y * gx;
  int wg = (bid & 7) * (nwg >> 3) + (bid >> 3);   // nwg % 8 == 0 for our grids
  bx = wg % gx; by = wg / gx;
}

__global__ __launch_bounds__(512, 2) void gemm256_gelu(const bf16* __restrict__ A,
                                                       const bf16* __restrict__ Bt,
                                                       const bf16* __restrict__ bias,
                                                       bf16* __restrict__ C,
                                                       int N, int K) {
  __shared__ alignas(16) bf16 sm[65536];   // 128 KiB
  int bx, by; xcd_swizzle(bx, by);
  int m0 = by * 256, n0 = bx * 256;
  f32x4 acc[8][4] = {};
  gemm256_core(A, Bt, K, K, K, m0, n0, sm, acc);

  int t = threadIdx.x, wave = t >> 6, lane = t & 63, quad = lane >> 4, l16 = lane & 15;
  int wm = (wave & 1) * 128, wn = (wave >> 1) * 64;
#pragma unroll
  for (int i = 0; i < 8; i++)
#pragma unroll
    for (int j = 0; j < 4; j++) {
      int n = n0 + wn + j * 16 + l16;
      float bv = (float)bias[n];
#pragma unroll
      for (int r = 0; r < 4; r++) {
        int m = m0 + wm + i * 16 + quad * 4 + r;
        C[(size_t)m * N + n] = (bf16)gelu_f(acc[i][j][r] + bv);
      }
    }
}

// W2 split-K partial GEMM: grid (4 ntiles, 16 mtiles, 4 kslices); each block
// computes a 256x256 partial over K=1024 and writes bf16 to its slice buffer.
__global__ __launch_bounds__(512, 2) void gemm256_part(const bf16* __restrict__ A,
                                                       const bf16* __restrict__ Bt,
                                                       bf16* __restrict__ P0, bf16* __restrict__ P1,
                                                       bf16* __restrict__ P2, bf16* __restrict__ P3,
                                                       int lda) {
  __shared__ alignas(16) bf16 sm[65536];
  int m0 = blockIdx.y * 256, n0 = blockIdx.x * 256, kz = blockIdx.z;
  const bf16* Ak = A + (size_t)kz * 1024;
  const bf16* Bk = Bt + (size_t)kz * 1024;
  f32x4 acc[8][4] = {};
  gemm256_core(Ak, Bk, 1024, lda, lda, m0, n0, sm, acc);

  bf16* P = (kz == 0) ? P0 : (kz == 1) ? P1 : (kz == 2) ? P2 : P3;
  int t = threadIdx.x, wave = t >> 6, lane = t & 63, quad = lane >> 4, l16 = lane & 15;
  int wm = (wave & 1) * 128, wn = (wave >> 1) * 64;
#pragma unroll
  for (int i = 0; i < 8; i++)
#pragma unroll
    for (int j = 0; j < 4; j++) {
      int n = n0 + wn + j * 16 + l16;
#pragma unroll
      for (int r = 0; r < 4; r++) {
        int m = m0 + wm + i * 16 + quad * 4 + r;
        P[(size_t)m * 1024 + n] = (bf16)acc[i][j][r];
      }
    }
}

// W2 reduce: out = sum(4 partials) + bias + residual (fp32 out).
__global__ __launch_bounds__(256) void w2_reduce(const bf16* __restrict__ P0, const bf16* __restrict__ P1,
                                                 const bf16* __restrict__ P2, const bf16* __restrict__ P3,
                                                 const float* __restrict__ res, const bf16* __restrict__ bias,
                                                 float* __restrict__ out) {
  int c = threadIdx.x * 4;
  size_t base = (size_t)blockIdx.x * 1024 + c;
  bf16x4 a0 = *(const bf16x4*)&P0[base];
  bf16x4 a1 = *(const bf16x4*)&P1[base];
  bf16x4 a2 = *(const bf16x4*)&P2[base];
  bf16x4 a3 = *(const bf16x4*)&P3[base];
  f32x4 rv = *(const f32x4*)&res[base];
  f32x4 o;
#pragma unroll
  for (int i = 0; i < 4; i++)
    o[i] = ((float)a0[i] + (float)a1[i]) + ((float)a2[i] + (float)a3[i]) + rv[i] + (float)bias[c + i];
  *(f32x4*)&out[base] = o;
}

// QKV GEMM (256x256 8-phase). Q cols (n<1024) pre-scaled by 0.125*log2(e)
// (softmax in log2 domain -> native exp2). V cols (n>=2048) written
// transposed AND kv-permuted within 16-token groups (quartets 1<->2), so
// the attn PV B-reads are contiguous b128 matching P's native register
// order (permutation g is an involution; position p holds token g(p)).
__global__ __launch_bounds__(512, 2) void gemm256_qkv(const bf16* __restrict__ A,
                                                      const bf16* __restrict__ Bt,
                                                      const bf16* __restrict__ bias,
                                                      bf16* __restrict__ QK,
                                                      bf16* __restrict__ Vt) {
  __shared__ alignas(16) bf16 sm[65536];
  int bx, by; xcd_swizzle(bx, by);
  int m0 = by * 256, n0 = bx * 256;
  f32x4 acc[8][4] = {};
  gemm256_core(A, Bt, 1024, 1024, 1024, m0, n0, sm, acc);

  int t = threadIdx.x, wave = t >> 6, lane = t & 63, quad = lane >> 4, l16 = lane & 15;
  int wm = (wave & 1) * 128, wn = (wave >> 1) * 64;
#pragma unroll
  for (int i = 0; i < 8; i++)
#pragma unroll
    for (int j = 0; j < 4; j++) {
      int n = n0 + wn + j * 16 + l16;
      float bv = (float)bias[n];
      int mb = m0 + wm + i * 16 + quad * 4;
      if (n < 1024) {
#pragma unroll
        for (int r = 0; r < 4; r++)
          QK[(size_t)(mb + r) * 2048 + n] = (bf16)((acc[i][j][r] + bv) * 0.18033688011112042f);
      } else if (n < 2048) {
#pragma unroll
        for (int r = 0; r < 4; r++)
          QK[(size_t)(mb + r) * 2048 + n] = (bf16)(acc[i][j][r] + bv);
      } else {
        int qt = (mb >> 2) & 3;                       // quartet within 16-group
        int qt2 = ((qt & 1) << 1) | (qt >> 1);        // swap quartets 1<->2
        int mb2 = (mb & ~15) | (qt2 << 2);
        bf16x4 pk;
#pragma unroll
        for (int r = 0; r < 4; r++) pk[r] = (bf16)(acc[i][j][r] + bv);
        *(bf16x4*)&Vt[(size_t)(n - 2048) * TOKENS + mb2] = pk;
      }
    }
}

// ------------------------------------------------------------------
// Flash attention v9: 8 waves / 512 threads per block. Waves 0-3 (str 0)
// and 4-7 (str 1) process DISJOINT kv halves (1024 each) of the SAME
// 128-row q-tile, each stream double-buffered in its own 32KB LDS lane
// -> 16 waves/CU (2x v8's occupancy) at identical LDS-read/MFMA/VALU
// totals. Partial (accO, accL) merge in-block through LDS at the end:
// O = (Oa+Ob)/(La+Lb) (no max-tracking needed; scores are O(1), exact).
// All v8 techniques retained: swapped QK^T, in-register P, pre-permuted
// Vt, conflict-free b128, setprio.
// ------------------------------------------------------------------
__global__ __launch_bounds__(512, 2) void attn_kernel(const bf16* __restrict__ QK,
                                                      const bf16* __restrict__ Vt,
                                                      bf16* __restrict__ O) {
  __shared__ alignas(16) bf16 KV[2][2][8192];  // [stream][buf]: K@0, V@4096
  int bid = blockIdx.x;
  int xcd = bid & 7, slot = bid >> 3;          // XCD-colocate (h,b) groups
  int g = xcd + 8 * (slot >> 4);
  int q0 = (slot & 15) * 128;
  int h = g & 15, b = g >> 4;
  int t = threadIdx.x, wave = t >> 6, lane = t & 63;
  int ws4 = wave & 3, str = wave >> 2;
  int l31 = lane & 31, l5 = lane >> 5, l7 = lane & 7;

  const bf16* Qg = QK;
  const bf16* Kg = QK + 1024;
  const size_t bT = (size_t)b * TSEQ;
  const int h64 = h * 64;
  const int tb0 = str * 16;                    // this stream's kv tile base

  int sr = lane >> 3;                 // 0..7
  int sch = l7 ^ sr;                  // pre-swizzled global chunk
  auto stage = [&](int tile, int buf) {
    int gt = tb0 + tile;
    size_t krow = bT + gt * 64 + ws4 * 8 + sr;
    bf16* kd = &KV[str][buf][ws4 * 512 + lane * 8];
    glds16(&Kg[krow * 2048 + h64 + sch * 8], kd);
    glds16(&Kg[(krow + 32) * 2048 + h64 + sch * 8], kd + 2048);
    size_t vrow = (size_t)(h64 + ws4 * 8 + sr) * TOKENS + bT + gt * 64 + sch * 8;
    glds16(&Vt[vrow], kd + 4096);
    glds16(&Vt[vrow + (size_t)32 * TOKENS], kd + 6144);
  };

  // Q fragments (B-operand of swapped QK^T): col = q = l31, k = l5*8+j
  bf16x8 qf[4];
  {
    size_t qrow = bT + q0 + ws4 * 32 + l31;
    const bf16* qp = &Qg[qrow * 2048 + h64 + l5 * 8];
#pragma unroll
    for (int ds = 0; ds < 4; ds++) qf[ds] = *(const bf16x8*)(qp + ds * 16);
  }

  // conflict-free b128 offsets (same form for K and V reads)
  int off[4];
#pragma unroll
  for (int w = 0; w < 4; w++) off[w] = l31 * 64 + (((w * 2 + l5) ^ l7) * 8);

  f32x16 accO0 = {}, accO1 = {}, accL = {};
  const bf16 one = (bf16)1.0f;
  const bf16x8 onesv = {one, one, one, one, one, one, one, one};

  stage(0, 0);
  __syncthreads();

  for (int it = 0; it < 16; it++) {
    int cur = it & 1;
    if (it + 1 < 16) stage(it + 1, cur ^ 1);
    const bf16* KB = &KV[str][cur][0];

    // S^T = K Q^T
    f32x16 st0 = {}, st1 = {};
    __builtin_amdgcn_s_setprio(1);
#pragma unroll
    for (int ds = 0; ds < 4; ds++) {
      bf16x8 k0 = *(const bf16x8*)&KB[off[ds]];
      bf16x8 k1 = *(const bf16x8*)&KB[off[ds] + 2048];
      st0 = __builtin_amdgcn_mfma_f32_32x32x16_bf16(k0, qf[ds], st0, 0, 0, 0);
      st1 = __builtin_amdgcn_mfma_f32_32x32x16_bf16(k1, qf[ds], st1, 0, 0, 0);
    }
    __builtin_amdgcn_s_setprio(0);

    // P = exp2(S^T) in native register order (matches permuted V)
    bf16x8 pa[4];
#pragma unroll
    for (int j = 0; j < 8; j++) {
      pa[0][j] = (bf16)exp2f(fminf(st0[j], 86.f));
      pa[1][j] = (bf16)exp2f(fminf(st0[8 + j], 86.f));
      pa[2][j] = (bf16)exp2f(fminf(st1[j], 86.f));
      pa[3][j] = (bf16)exp2f(fminf(st1[8 + j], 86.f));
    }

    // O += P V ; L += P 1
    __builtin_amdgcn_s_setprio(1);
#pragma unroll
    for (int w = 0; w < 4; w++) {
      bf16x8 v0 = *(const bf16x8*)&KB[off[w] + 4096];
      bf16x8 v1 = *(const bf16x8*)&KB[off[w] + 6144];
      accO0 = __builtin_amdgcn_mfma_f32_32x32x16_bf16(pa[w], v0, accO0, 0, 0, 0);
      accO1 = __builtin_amdgcn_mfma_f32_32x32x16_bf16(pa[w], v1, accO1, 0, 0, 0);
      accL  = __builtin_amdgcn_mfma_f32_32x32x16_bf16(pa[w], onesv, accL, 0, 0, 0);
    }
    __builtin_amdgcn_s_setprio(0);

    __syncthreads();
  }

  // ---- in-block combine of the two kv-half partials through LDS ----
  float* cb = (float*)&KV[0][0][0];   // 48KB used of 64KB (staging is dead)
  if (str == 1) {
    int base = ws4 * 3072 + lane * 16;
    *(f32x16*)&cb[base]        = accO0;
    *(f32x16*)&cb[base + 1024] = accO1;
    *(f32x16*)&cb[base + 2048] = accL;
  }
  __syncthreads();
  if (str == 0) {
    int base = ws4 * 3072 + lane * 16;
    f32x16 o0 = *(const f32x16*)&cb[base];
    f32x16 o1 = *(const f32x16*)&cb[base + 1024];
    f32x16 ll = *(const f32x16*)&cb[base + 2048];
#pragma unroll
    for (int r = 0; r < 16; r++) {
      int q = (r & 3) + 8 * (r >> 2) + 4 * l5;
      float rl = 1.0f / fmaxf(accL[r] + ll[r], 1e-30f);
      size_t orow = (bT + q0 + ws4 * 32 + q) * CDIM + h64;
      O[orow + l31]      = (bf16)((accO0[r] + o0[r]) * rl);
      O[orow + 32 + l31] = (bf16)((accO1[r] + o1[r]) * rl);
    }
  }
}

// ------------------------------------------------------------------
extern "C" void kernel_launch(void* const* d_in, const int* in_sizes, int n_in,
                              void* d_out, int out_size, void* d_ws, size_t ws_size,
                              hipStream_t stream) {
  char* ws = (char*)d_ws;
  const size_t MB = 1024 * 1024;
  const size_t KB = 1024;

  int* flags = (int*)ws;
  bf16* vec_c = (bf16*)(ws + 4 * KB);
  bf16* ln1g_c = vec_c + 0 * 8192;
  bf16* ln1b_c = vec_c + 1 * 8192;
  bf16* ln2g_c = vec_c + 2 * 8192;
  bf16* ln2b_c = vec_c + 3 * 8192;
  bf16* bqkv_c = vec_c + 4 * 8192;            // [3072]: bq | bk | bv
  bf16* bo_c   = vec_c + 6 * 8192;
  bf16* b1_c   = vec_c + 7 * 8192;
  bf16* b2_c   = vec_c + 8 * 8192;

  bf16*  WqkvT  = (bf16*)(ws + 1 * MB);       // [3072][1024]  1-7   (dead after QKV)
  bf16*  WoT    = (bf16*)(ws + 7 * MB);       // 7-9   (dead after Wo)
  bf16*  W1T    = (bf16*)(ws + 9 * MB);       // 9-17  (dead after FFN1)
  bf16*  W2T    = (bf16*)(ws + 17 * MB);      // 17-25 (live to end)
  bf16*  xn     = (bf16*)(ws + 25 * MB);      // 25-33 (dead after Wo)
  bf16*  QKbuf  = (bf16*)(ws + 33 * MB);      // [4096][2048] 33-49 (dead after attn)
  bf16*  Vtbuf  = (bf16*)(ws + 49 * MB);      // [1024][4096] 49-57 (dead after attn)
  bf16*  ab     = (bf16*)(ws + 57 * MB);      // 57-65 (dead after Wo)
  float* xmid32 = (float*)(ws + 65 * MB);     // 65-81 fp32 (live to end)
  bf16*  h2     = (bf16*)(ws + 81 * MB);      // 81-89 (dead after FFN1)
  bf16*  f1     = (bf16*)(ws + 33 * MB);      // [4096][4096] 33-65 (live to end of W2)
  // W2 split-K partials (8 MB each) -- ONLY in regions dead at W2 time and
  // DISJOINT from f1 (33-65) and xmid32 (65-81): race fix vs round 4.
  bf16*  pk0    = (bf16*)(ws + 25 * MB);      // xn region (dead after Wo)
  bf16*  pk1    = (bf16*)(ws + 81 * MB);      // h2 region (dead after FFN1)
  bf16*  pk2    = (bf16*)(ws + 1 * MB);       // WqkvT region (dead after QKV)
  bf16*  pk3    = (bf16*)(ws + 9 * MB);       // W1T region (dead after FFN1)

  // flag idx: 0 x,1 ln1g,2 ln1b,3 ln2g,4 ln2b,5 Wq,6 bq,7 Wk,8 bk,9 Wv,10 bv,
  //           11 Wo,12 bo,13 W1,14 b1,15 W2,16 b2
  const int din_idx[NBUF] = {0, 2, 3, 4, 5, 6, 7, 8, 9, 10, 11, 12, 13, 14, 15, 16, 17};
  DetectArgs da;
  for (int i = 0; i < NBUF; i++) { da.p[i] = d_in[din_idx[i]]; da.n[i] = in_sizes[din_idx[i]]; }
  detect_kernel<<<NBUF, 256, 0, stream>>>(da, flags);

  // ---- mega preprocessing: transposes + vec converts + LN1, one launch ----
  MegaArgs ma;
  {
    const void* wi[6] = {d_in[6], d_in[8], d_in[10], d_in[12], d_in[14], d_in[16]};
    bf16* wo[6] = {WqkvT, WqkvT + 1024 * 1024, WqkvT + 2 * 1024 * 1024, WoT, W1T, W2T};
    const int wK[6] = {1024, 1024, 1024, 1024, 1024, 4096};
    const int wN[6] = {1024, 1024, 1024, 1024, 4096, 1024};
    const int wf[6] = {5, 7, 9, 11, 13, 15};
    for (int i = 0; i < 6; i++) {
      ma.w_in[i] = wi[i]; ma.w_out[i] = wo[i];
      ma.wK[i] = wK[i]; ma.wN[i] = wN[i]; ma.wflag[i] = wf[i];
    }
    const int vf[10] = {1, 2, 3, 4, 6, 8, 10, 12, 14, 16};
    bf16* vd[10] = {ln1g_c, ln1b_c, ln2g_c, ln2b_c,
                    bqkv_c, bqkv_c + 1024, bqkv_c + 2048, bo_c, b1_c, b2_c};
    for (int i = 0; i < 10; i++) {
      int di = din_idx[vf[i]];
      ma.vp[i] = d_in[di]; ma.vd[i] = vd[i]; ma.vn[i] = in_sizes[di]; ma.vfi[i] = vf[i];
    }
    ma.x = d_in[0]; ma.graw = d_in[2]; ma.braw = d_in[3]; ma.y = xn;
  }
  mega_pre<<<3072 + 1 + TOKENS, dim3(64, 4), 0, stream>>>(ma, flags);

  // ---- pipeline ----
  // QKV: M=4096, N=3072, K=1024 -> grid 12x16 = 192 blocks (8-phase 256²)
  gemm256_qkv<<<dim3(12, 16), 512, 0, stream>>>(xn, WqkvT, bqkv_c, QKbuf, Vtbuf);

  attn_kernel<<<512, 512, 0, stream>>>(QKbuf, Vtbuf, ab);

  gemm128<64, 128, EPI_RES, float, bf16><<<dim3(8, 64), 256, 0, stream>>>(
      ab, WoT, bo_c, xn, xmid32, 1024, 1024);

  ln_f32<<<TOKENS, 256, 0, stream>>>(xmid32, ln2g_c, ln2b_c, h2);

  // FFN1: M=4096, N=4096, K=1024 -> grid 16x16 = 256 blocks (8-phase 256²)
  gemm256_gelu<<<dim3(16, 16), 512, 0, stream>>>(h2, W1T, b1_c, f1, 4096, 1024);

  // FFN2 (W2): split-K=4 8-phase 256² (grid 4x16x4 = 256 blocks) + reduce
  gemm256_part<<<dim3(4, 16, 4), 512, 0, stream>>>(f1, W2T, pk0, pk1, pk2, pk3, 4096);
  w2_reduce<<<TOKENS, 256, 0, stream>>>(pk0, pk1, pk2, pk3, xmid32, b2_c, (float*)d_out);
}

// Round 7
// 368.140 us; speedup vs baseline: 1.0121x; 1.0121x over previous
//
#include <hip/hip_runtime.h>
#include <cstdint>
#include <cstddef>

typedef __bf16 bf16;
typedef __bf16 bf16x8 __attribute__((ext_vector_type(8)));
typedef __bf16 bf16x4 __attribute__((ext_vector_type(4)));
typedef float f32x4 __attribute__((ext_vector_type(4)));
typedef float f32x16 __attribute__((ext_vector_type(16)));

#define TOKENS 4096   // B*T
#define TSEQ   2048
#define NHEADS 16
#define HDIM   64
#define CDIM   1024

// ---- async global->LDS, 16B per lane ----
typedef __attribute__((address_space(3))) unsigned int lds_uint;
typedef __attribute__((address_space(1))) const unsigned int g_uint;
__device__ __forceinline__ void glds16(const bf16* g, bf16* l) {
  __builtin_amdgcn_global_load_lds((g_uint*)g, (lds_uint*)l, 16, 0, 0);
}

// fast GELU: x*sigmoid(1.5957691x + 0.0713548x^3); max dev from erf-GELU ~3e-4
__device__ __forceinline__ float gelu_f(float v) {
  float g2 = v * (1.5957691216f + 0.0713548163f * v * v);
  return v / (1.0f + __expf(-g2));
}

// ------------------------------------------------------------------
// Input dtype detection (insurance; fp32 -> flag 0).
// ------------------------------------------------------------------
#define NBUF 17
struct DetectArgs { const void* p[NBUF]; int n[NBUF]; };

__global__ __launch_bounds__(256) void detect_kernel(DetectArgs a, int* __restrict__ flags) {
  __shared__ int s_nz, s_bl;
  if (threadIdx.x == 0) { s_nz = 0; s_bl = 0; }
  __syncthreads();
  int i = blockIdx.x;
  const unsigned int* w = (const unsigned int*)a.p[i];
  int nwords = a.n[i] / 2; if (nwords > 2048) nwords = 2048;
  int nz = 0, bl = 0;
  for (int j = threadIdx.x; j < nwords; j += 256) {
    unsigned int v = w[j];
    if (v != 0u) {
      nz++;
      unsigned int e = (v >> 7) & 0xFFu;
      if (e >= 100u && e <= 140u) bl++;
    }
  }
  atomicAdd(&s_nz, nz);
  atomicAdd(&s_bl, bl);
  __syncthreads();
  if (threadIdx.x == 0) flags[i] = (2 * s_bl >= s_nz) ? 1 : 0;
}

__device__ __forceinline__ float ld_any(const void* p, size_t idx, bool isb) {
  return isb ? (float)((const bf16*)p)[idx] : ((const float*)p)[idx];
}

// ------------------------------------------------------------------
// LayerNorm stats (rows of 1024, 256 threads): returns mu, rstd
// ------------------------------------------------------------------
__device__ __forceinline__ void ln_stats(float s, float s2, int tid, float& mu, float& rstd) {
#pragma unroll
  for (int off = 32; off; off >>= 1) {
    s  += __shfl_down(s, off);
    s2 += __shfl_down(s2, off);
  }
  __shared__ float red[8];
  int w = tid >> 6;
  if ((tid & 63) == 0) { red[w] = s; red[4 + w] = s2; }
  __syncthreads();
  if (tid == 0) {
    red[0] = red[0] + red[1] + red[2] + red[3];
    red[4] = red[4] + red[5] + red[6] + red[7];
  }
  __syncthreads();
  mu = red[0] * (1.0f / CDIM);
  float var = fmaxf(red[4] * (1.0f / CDIM) - mu * mu, 0.f);
  rstd = rsqrtf(var + 1e-5f);
}

__global__ __launch_bounds__(256) void ln_f32(const float* __restrict__ x,
                                              const bf16* __restrict__ g,
                                              const bf16* __restrict__ b,
                                              bf16* __restrict__ y) {
  int row = blockIdx.x, tid = threadIdx.x;
  float v[4]; float s = 0.f, s2 = 0.f;
#pragma unroll
  for (int i = 0; i < 4; i++) {
    float f = x[(size_t)row * CDIM + tid * 4 + i];
    v[i] = f; s += f; s2 += f * f;
  }
  float mu, rstd;
  ln_stats(s, s2, tid, mu, rstd);
  bf16* yr = y + (size_t)row * CDIM;
#pragma unroll
  for (int i = 0; i < 4; i++) {
    int c = tid * 4 + i;
    yr[c] = (bf16)((v[i] - mu) * rstd * (float)g[c] + (float)b[c]);
  }
}

// ------------------------------------------------------------------
// Mega preprocessing kernel (ONE launch): 6 weight transposes (+convert),
// 10 small-vector converts, LN1 over 4096 rows.
// ------------------------------------------------------------------
struct MegaArgs {
  const void* w_in[6]; bf16* w_out[6]; int wK[6], wN[6], wflag[6];
  const void* vp[10]; bf16* vd[10]; int vn[10], vfi[10];
  const void* x; const void* graw; const void* braw; bf16* y;
};

__global__ __launch_bounds__(256) void mega_pre(MegaArgs a, const int* __restrict__ flags) {
  int bid = blockIdx.x;
  int tx = threadIdx.x, ty = threadIdx.y;          // blockDim (64,4)
  int tid = tx + ty * 64;
  if (bid < 3072) {
    __shared__ bf16 tile[64][65];
    int mi, start;
    if (bid < 1024)      { mi = bid >> 8; start = mi << 8; }
    else if (bid < 2048) { mi = 4; start = 1024; }
    else                 { mi = 5; start = 2048; }
    int tb = bid - start;
    int nT = a.wN[mi] >> 6;
    int kb = (tb / nT) * 64, nb = (tb % nT) * 64;
    int K = a.wK[mi], N = a.wN[mi];
    bool isb = flags[a.wflag[mi]] != 0;
    const void* in = a.w_in[mi]; bf16* out = a.w_out[mi];
    for (int i = ty; i < 64; i += 4)
      tile[i][tx] = (bf16)ld_any(in, (size_t)(kb + i) * N + nb + tx, isb);
    __syncthreads();
    for (int i = ty; i < 64; i += 4)
      out[(size_t)(nb + i) * K + kb + tx] = tile[tx][i];
  } else if (bid == 3072) {
    for (int i = 0; i < 10; i++) {
      bool isb = flags[a.vfi[i]] != 0;
      const void* in = a.vp[i]; bf16* out = a.vd[i]; int n = a.vn[i];
      for (int j = tid; j < n; j += 256)
        out[j] = (bf16)ld_any(in, j, isb);
    }
  } else {
    int row = bid - 3073;
    bool isb  = flags[0] != 0;
    bool gisb = flags[1] != 0;
    bool bisb = flags[2] != 0;
    float v[4]; float s = 0.f, s2 = 0.f;
#pragma unroll
    for (int i = 0; i < 4; i++) {
      float f = ld_any(a.x, (size_t)row * CDIM + tid * 4 + i, isb);
      v[i] = f; s += f; s2 += f * f;
    }
    float mu, rstd;
    ln_stats(s, s2, tid, mu, rstd);
    bf16* yr = a.y + (size_t)row * CDIM;
#pragma unroll
    for (int i = 0; i < 4; i++) {
      int c = tid * 4 + i;
      float gv = ld_any(a.graw, c, gisb);
      float bv = ld_any(a.braw, c, bisb);
      yr[c] = (bf16)((v[i] - mu) * rstd * gv + bv);
    }
  }
}

// ------------------------------------------------------------------
// Legacy GEMM core (BM<=128): single-buffer 2-barrier. Kept for Wo.
// ------------------------------------------------------------------
template <int BM, int BN>
__device__ __forceinline__ void gemm_core(const bf16* __restrict__ A,
                                          const bf16* __restrict__ Bt,
                                          int K, int m0, int n0,
                                          bf16* As, bf16* Bs,
                                          f32x4 (&acc)[BM / 32][BN / 32]) {
  constexpr int SI = BM / 32, SJ = BN / 32;
  int t = threadIdx.x;
  int wave = t >> 6, lane = t & 63, quad = lane >> 4, l16 = lane & 15;
  int wm = (wave & 1) * (BM / 2), wn = (wave >> 1) * (BN / 2);
  int srow = t >> 2, sc = t & 3;
  int swz = (srow >> 1) & 3;
  const bf16* ga[BM / 64];
  const bf16* gb[BN / 64];
#pragma unroll
  for (int h = 0; h < BM / 64; h++)
    ga[h] = A + (size_t)(m0 + h * 64 + srow) * K + (sc ^ swz) * 8;
#pragma unroll
  for (int h = 0; h < BN / 64; h++)
    gb[h] = Bt + (size_t)(n0 + h * 64 + srow) * K + (sc ^ swz) * 8;

  for (int k0 = 0; k0 < K; k0 += 64) {
#pragma unroll
    for (int q = 0; q < 2; q++) {
#pragma unroll
      for (int h = 0; h < BM / 64; h++)
        glds16(ga[h] + k0 + q * 32, As + q * (BM * 32) + h * 2048 + srow * 32 + sc * 8);
#pragma unroll
      for (int h = 0; h < BN / 64; h++)
        glds16(gb[h] + k0 + q * 32, Bs + q * (BN * 32) + h * 2048 + srow * 32 + sc * 8);
    }
    __syncthreads();
#pragma unroll
    for (int q = 0; q < 2; q++) {
      bf16x8 af[SI], bfr[SJ];
#pragma unroll
      for (int i = 0; i < SI; i++) {
        int m = wm + i * 16 + l16;
        af[i] = *(const bf16x8*)&As[q * (BM * 32) + m * 32 + ((quad ^ ((m >> 1) & 3)) * 8)];
      }
#pragma unroll
      for (int j = 0; j < SJ; j++) {
        int n = wn + j * 16 + l16;
        bfr[j] = *(const bf16x8*)&Bs[q * (BN * 32) + n * 32 + ((quad ^ ((n >> 1) & 3)) * 8)];
      }
#pragma unroll
      for (int i = 0; i < SI; i++)
#pragma unroll
        for (int j = 0; j < SJ; j++)
          acc[i][j] = __builtin_amdgcn_mfma_f32_16x16x32_bf16(af[i], bfr[j], acc[i][j], 0, 0, 0);
    }
    __syncthreads();
  }
}

#define EPI_NONE 0
#define EPI_RES  1
#define EPI_GELU 2

template <int BM, int BN, int EPI, typename OutT, typename ResT>
__global__ __launch_bounds__(256) void gemm128(const bf16* __restrict__ A,
                                               const bf16* __restrict__ Bt,
                                               const bf16* __restrict__ bias,
                                               const ResT* __restrict__ res,
                                               OutT* __restrict__ C,
                                               int N, int K) {
  __shared__ alignas(16) bf16 As[2 * BM * 32];
  __shared__ alignas(16) bf16 Bs[2 * BN * 32];
  int m0 = blockIdx.y * BM, n0 = blockIdx.x * BN;
  f32x4 acc[BM / 32][BN / 32] = {};
  gemm_core<BM, BN>(A, Bt, K, m0, n0, As, Bs, acc);

  int t = threadIdx.x, wave = t >> 6, lane = t & 63, quad = lane >> 4, l16 = lane & 15;
  int wm = (wave & 1) * (BM / 2), wn = (wave >> 1) * (BN / 2);
#pragma unroll
  for (int i = 0; i < BM / 32; i++)
#pragma unroll
    for (int j = 0; j < BN / 32; j++) {
      int n = n0 + wn + j * 16 + l16;
      float bv = (float)bias[n];
#pragma unroll
      for (int r = 0; r < 4; r++) {
        int m = m0 + wm + i * 16 + quad * 4 + r;
        float v = acc[i][j][r] + bv;
        if (EPI == EPI_GELU)      v = gelu_f(v);
        else if (EPI == EPI_RES)  v += (float)res[(size_t)m * N + n];
        C[(size_t)m * N + n] = (OutT)v;
      }
    }
}

// ------------------------------------------------------------------
// 256x256 8-phase GEMM core (T2+T3+T4+T5): 512 threads = 8 waves (2Mx4N),
// per-wave 128x64 output, BK=64, 128 KiB double-buffered LDS, counted
// vmcnt(6) only at phases 4/8. lda/ldb allow K-sliced operands.
// ------------------------------------------------------------------
__device__ __forceinline__ void gemm256_core(const bf16* __restrict__ A,
                                             const bf16* __restrict__ Bt,
                                             int K, int lda, int ldb, int m0, int n0,
                                             bf16* sm, f32x4 (&acc)[8][4]) {
  const int NT = K >> 6;
  const int t = threadIdx.x;
  const int lane = t & 63, quad = lane >> 4, l16 = lane & 15;
  const int wave = t >> 6;
  const int wm = (wave & 1) * 128, wn = (wave >> 1) * 64;
  const int srow = t >> 2, sc = t & 3;
  const int swz = (srow >> 1) & 3;
  const int rA = (srow & 63) + ((srow >> 6) << 7);   // A-u1 row; u2 = +64
  const bf16* gA = A + (size_t)(m0 + rA) * lda + ((sc ^ swz) << 3);
  const bf16* gB = Bt + (size_t)(n0 + srow) * ldb + ((sc ^ swz) << 3);
  const int ldsA = rA * 32 + sc * 8;
  const int ldsB = srow * 32 + sc * 8;

  auto stA = [&](int tile, int u) {   // u: 0 = rows [0,64)+[128,192), 1 = +64
    if (tile >= NT) return;
    const bf16* g = gA + (size_t)(u << 6) * lda + (tile << 6);
    bf16* l = sm + ((tile & 1) << 15) + ldsA + (u << 11);
    glds16(g, l);
    glds16(g + 32, l + 8192);
  };
  auto stB = [&](int tile, int h) {   // h: 0 = rows [0,128), 1 = [128,256)
    if (tile >= NT) return;
    const bf16* g = gB + (size_t)(h << 7) * ldb + (tile << 6);
    bf16* l = sm + ((tile & 1) << 15) + 16384 + ldsB + (h << 12);
    glds16(g, l);
    glds16(g + 32, l + 8192);
  };

  // prologue: mimic steady-state (j-1)P2..P8, end with vmcnt(6)+barrier
  stB(0, 0); stB(0, 1); stA(0, 0); stA(0, 1);
  stB(1, 0); stB(1, 1); stA(1, 0);
  asm volatile("s_waitcnt vmcnt(6)" ::: "memory");
  __builtin_amdgcn_s_barrier();
  asm volatile("" ::: "memory");

  bf16x8 bfr[2][4];

#define LDB256(buf)                                                        \
  _Pragma("unroll") for (int q = 0; q < 2; q++)                            \
  _Pragma("unroll") for (int j = 0; j < 4; j++) {                          \
    int nl = wn + j * 16 + l16;                                            \
    bfr[q][j] = *(const bf16x8*)&sm[((buf) << 15) + 16384 + q * 8192 +     \
                                    nl * 32 + ((quad ^ ((nl >> 1) & 3)) << 3)]; \
  }

#define PHASE256(buf, P, STAGE, EXTRAWAIT)                                 \
  {                                                                        \
    bf16x8 af[2][2];                                                       \
    _Pragma("unroll") for (int q = 0; q < 2; q++)                          \
    _Pragma("unroll") for (int i2 = 0; i2 < 2; i2++) {                     \
      int ml = wm + (P) * 32 + i2 * 16 + l16;                              \
      af[q][i2] = *(const bf16x8*)&sm[((buf) << 15) + q * 8192 + ml * 32 + \
                                      ((quad ^ ((ml >> 1) & 3)) << 3)];    \
    }                                                                      \
    if ((P) == 0) { LDB256(buf); }                                         \
    STAGE;                                                                 \
    asm volatile("" ::: "memory");                                         \
    __builtin_amdgcn_s_barrier();                                          \
    asm volatile("s_waitcnt lgkmcnt(0)" ::: "memory");                     \
    __builtin_amdgcn_s_setprio(1);                                         \
    _Pragma("unroll") for (int q = 0; q < 2; q++)                          \
    _Pragma("unroll") for (int i2 = 0; i2 < 2; i2++)                       \
    _Pragma("unroll") for (int j = 0; j < 4; j++)                          \
      acc[(P) * 2 + i2][j] = __builtin_amdgcn_mfma_f32_16x16x32_bf16(      \
          af[q][i2], bfr[q][j], acc[(P) * 2 + i2][j], 0, 0, 0);            \
    __builtin_amdgcn_s_setprio(0);                                         \
    asm volatile("" ::: "memory");                                         \
    EXTRAWAIT;                                                             \
    __builtin_amdgcn_s_barrier();                                          \
    asm volatile("" ::: "memory");                                         \
  }

  for (int t0 = 0; t0 < NT; t0 += 2) {
    const int t1 = t0 + 1;
    PHASE256(0, 0, stA(t1, 1), (void)0);
    PHASE256(0, 1, stB(t0 + 2, 0), (void)0);
    PHASE256(0, 2, stB(t0 + 2, 1), (void)0);
    PHASE256(0, 3, stA(t0 + 2, 0),
             asm volatile("s_waitcnt vmcnt(6)" ::: "memory"));
    PHASE256(1, 0, stA(t0 + 2, 1), (void)0);
    PHASE256(1, 1, stB(t1 + 2, 0), (void)0);
    PHASE256(1, 2, stB(t1 + 2, 1), (void)0);
    PHASE256(1, 3, stA(t1 + 2, 0),
             asm volatile("s_waitcnt vmcnt(6)" ::: "memory"));
  }
#undef PHASE256
#undef LDB256
}

__device__ __forceinline__ void xcd_swizzle(int& bx, int& by) {
  int gx = gridDim.x;
  int nwg = gx * gridDim.y;
  int bid = blockIdx.x + blockIdx.y * gx;
  int wg = (bid & 7) * (nwg >> 3) + (bid >> 3);   // nwg % 8 == 0 for our grids
  bx = wg % gx; by = wg / gx;
}

__global__ __launch_bounds__(512, 2) void gemm256_gelu(const bf16* __restrict__ A,
                                                       const bf16* __restrict__ Bt,
                                                       const bf16* __restrict__ bias,
                                                       bf16* __restrict__ C,
                                                       int N, int K) {
  __shared__ alignas(16) bf16 sm[65536];   // 128 KiB
  int bx, by; xcd_swizzle(bx, by);
  int m0 = by * 256, n0 = bx * 256;
  f32x4 acc[8][4] = {};
  gemm256_core(A, Bt, K, K, K, m0, n0, sm, acc);

  int t = threadIdx.x, wave = t >> 6, lane = t & 63, quad = lane >> 4, l16 = lane & 15;
  int wm = (wave & 1) * 128, wn = (wave >> 1) * 64;
#pragma unroll
  for (int i = 0; i < 8; i++)
#pragma unroll
    for (int j = 0; j < 4; j++) {
      int n = n0 + wn + j * 16 + l16;
      float bv = (float)bias[n];
#pragma unroll
      for (int r = 0; r < 4; r++) {
        int m = m0 + wm + i * 16 + quad * 4 + r;
        C[(size_t)m * N + n] = (bf16)gelu_f(acc[i][j][r] + bv);
      }
    }
}

// W2 split-K partial GEMM: grid (4 ntiles, 16 mtiles, 4 kslices); each block
// computes a 256x256 partial over K=1024 and writes bf16 to its slice buffer.
__global__ __launch_bounds__(512, 2) void gemm256_part(const bf16* __restrict__ A,
                                                       const bf16* __restrict__ Bt,
                                                       bf16* __restrict__ P0, bf16* __restrict__ P1,
                                                       bf16* __restrict__ P2, bf16* __restrict__ P3,
                                                       int lda) {
  __shared__ alignas(16) bf16 sm[65536];
  int m0 = blockIdx.y * 256, n0 = blockIdx.x * 256, kz = blockIdx.z;
  const bf16* Ak = A + (size_t)kz * 1024;
  const bf16* Bk = Bt + (size_t)kz * 1024;
  f32x4 acc[8][4] = {};
  gemm256_core(Ak, Bk, 1024, lda, lda, m0, n0, sm, acc);

  bf16* P = (kz == 0) ? P0 : (kz == 1) ? P1 : (kz == 2) ? P2 : P3;
  int t = threadIdx.x, wave = t >> 6, lane = t & 63, quad = lane >> 4, l16 = lane & 15;
  int wm = (wave & 1) * 128, wn = (wave >> 1) * 64;
#pragma unroll
  for (int i = 0; i < 8; i++)
#pragma unroll
    for (int j = 0; j < 4; j++) {
      int n = n0 + wn + j * 16 + l16;
#pragma unroll
      for (int r = 0; r < 4; r++) {
        int m = m0 + wm + i * 16 + quad * 4 + r;
        P[(size_t)m * 1024 + n] = (bf16)acc[i][j][r];
      }
    }
}

// W2 reduce: out = sum(4 partials) + bias + residual (fp32 out).
__global__ __launch_bounds__(256) void w2_reduce(const bf16* __restrict__ P0, const bf16* __restrict__ P1,
                                                 const bf16* __restrict__ P2, const bf16* __restrict__ P3,
                                                 const float* __restrict__ res, const bf16* __restrict__ bias,
                                                 float* __restrict__ out) {
  int c = threadIdx.x * 4;
  size_t base = (size_t)blockIdx.x * 1024 + c;
  bf16x4 a0 = *(const bf16x4*)&P0[base];
  bf16x4 a1 = *(const bf16x4*)&P1[base];
  bf16x4 a2 = *(const bf16x4*)&P2[base];
  bf16x4 a3 = *(const bf16x4*)&P3[base];
  f32x4 rv = *(const f32x4*)&res[base];
  f32x4 o;
#pragma unroll
  for (int i = 0; i < 4; i++)
    o[i] = ((float)a0[i] + (float)a1[i]) + ((float)a2[i] + (float)a3[i]) + rv[i] + (float)bias[c + i];
  *(f32x4*)&out[base] = o;
}

// QKV GEMM (256x256 8-phase). Q cols (n<1024) pre-scaled by 0.125*log2(e)
// (softmax in log2 domain -> native exp2). V cols (n>=2048) written
// transposed AND kv-permuted within 16-token groups (quartets 1<->2), so
// the attn PV B-reads are contiguous b128 matching P's native register
// order (permutation g is an involution; position p holds token g(p)).
__global__ __launch_bounds__(512, 2) void gemm256_qkv(const bf16* __restrict__ A,
                                                      const bf16* __restrict__ Bt,
                                                      const bf16* __restrict__ bias,
                                                      bf16* __restrict__ QK,
                                                      bf16* __restrict__ Vt) {
  __shared__ alignas(16) bf16 sm[65536];
  int bx, by; xcd_swizzle(bx, by);
  int m0 = by * 256, n0 = bx * 256;
  f32x4 acc[8][4] = {};
  gemm256_core(A, Bt, 1024, 1024, 1024, m0, n0, sm, acc);

  int t = threadIdx.x, wave = t >> 6, lane = t & 63, quad = lane >> 4, l16 = lane & 15;
  int wm = (wave & 1) * 128, wn = (wave >> 1) * 64;
#pragma unroll
  for (int i = 0; i < 8; i++)
#pragma unroll
    for (int j = 0; j < 4; j++) {
      int n = n0 + wn + j * 16 + l16;
      float bv = (float)bias[n];
      int mb = m0 + wm + i * 16 + quad * 4;
      if (n < 1024) {
#pragma unroll
        for (int r = 0; r < 4; r++)
          QK[(size_t)(mb + r) * 2048 + n] = (bf16)((acc[i][j][r] + bv) * 0.18033688011112042f);
      } else if (n < 2048) {
#pragma unroll
        for (int r = 0; r < 4; r++)
          QK[(size_t)(mb + r) * 2048 + n] = (bf16)(acc[i][j][r] + bv);
      } else {
        int qt = (mb >> 2) & 3;                       // quartet within 16-group
        int qt2 = ((qt & 1) << 1) | (qt >> 1);        // swap quartets 1<->2
        int mb2 = (mb & ~15) | (qt2 << 2);
        bf16x4 pk;
#pragma unroll
        for (int r = 0; r < 4; r++) pk[r] = (bf16)(acc[i][j][r] + bv);
        *(bf16x4*)&Vt[(size_t)(n - 2048) * TOKENS + mb2] = pk;
      }
    }
}

// ------------------------------------------------------------------
// Flash attention v10 = v8 structure (4 waves, counted vmcnt(4), raw
// barriers, 2-tiles-ahead staging) with a 3-buffer 48KB ring instead of
// 4-buffer 64KB -> 3 blocks/CU (12 waves/CU, +50% independent-block TLP).
// Ring safety: WAR -- buf (it+2)%3 last read in iter it-1, barrier
// separates; RAW -- per-wave vmcnt(4) before barrier => stage(it+1)
// landed for every wave. Tail drains vmcnt(0) exactly like v8.
// ------------------------------------------------------------------
__global__ __launch_bounds__(256, 3) void attn_kernel(const bf16* __restrict__ QK,
                                                      const bf16* __restrict__ Vt,
                                                      bf16* __restrict__ O) {
  __shared__ alignas(16) bf16 KV[3][8192];   // per buf: K[64][64] @0, V[64][64] @4096
  int bid = blockIdx.x;
  int xcd = bid & 7, slot = bid >> 3;        // XCD-colocate (h,b) groups
  int g = xcd + 8 * (slot >> 4);
  int q0 = (slot & 15) * 128;
  int h = g & 15, b = g >> 4;
  int t = threadIdx.x, wave = t >> 6, lane = t & 63;
  int l31 = lane & 31, l5 = lane >> 5, l7 = lane & 7;

  const bf16* Qg = QK;
  const bf16* Kg = QK + 1024;
  const size_t bT = (size_t)b * TSEQ;
  const int h64 = h * 64;

  int sr = lane >> 3;                 // 0..7
  int sch = l7 ^ sr;                  // pre-swizzled global chunk
  auto stage = [&](int tile, int buf) {
    size_t krow = bT + tile * 64 + wave * 8 + sr;
    bf16* kd = &KV[buf][wave * 512 + lane * 8];
    glds16(&Kg[krow * 2048 + h64 + sch * 8], kd);
    glds16(&Kg[(krow + 32) * 2048 + h64 + sch * 8], kd + 2048);
    size_t vrow = (size_t)(h64 + wave * 8 + sr) * TOKENS + bT + tile * 64 + sch * 8;
    glds16(&Vt[vrow], kd + 4096);
    glds16(&Vt[vrow + (size_t)32 * TOKENS], kd + 6144);
  };

  // Q fragments (B-operand of swapped QK^T): col = q = l31, k = l5*8+j
  bf16x8 qf[4];
  {
    size_t qrow = bT + q0 + wave * 32 + l31;
    const bf16* qp = &Qg[qrow * 2048 + h64 + l5 * 8];
#pragma unroll
    for (int ds = 0; ds < 4; ds++) qf[ds] = *(const bf16x8*)(qp + ds * 16);
  }

  // conflict-free b128 offsets (same form for K and V reads)
  int off[4];
#pragma unroll
  for (int w = 0; w < 4; w++) off[w] = l31 * 64 + (((w * 2 + l5) ^ l7) * 8);

  f32x16 accO0 = {}, accO1 = {}, accL = {};
  const bf16 one = (bf16)1.0f;
  const bf16x8 onesv = {one, one, one, one, one, one, one, one};

  stage(0, 0);
  stage(1, 1);
  asm volatile("s_waitcnt vmcnt(4)" ::: "memory");
  __builtin_amdgcn_s_barrier();
  asm volatile("" ::: "memory");

  int cur = 0, sb = 2;                // read buf, stage buf for it+2
  for (int it = 0; it < TSEQ / 64; it++) {
    if (it + 2 < TSEQ / 64) stage(it + 2, sb);
    const bf16* KB = &KV[cur][0];

    // S^T = K Q^T
    f32x16 st0 = {}, st1 = {};
    __builtin_amdgcn_s_setprio(1);
#pragma unroll
    for (int ds = 0; ds < 4; ds++) {
      bf16x8 k0 = *(const bf16x8*)&KB[off[ds]];
      bf16x8 k1 = *(const bf16x8*)&KB[off[ds] + 2048];
      st0 = __builtin_amdgcn_mfma_f32_32x32x16_bf16(k0, qf[ds], st0, 0, 0, 0);
      st1 = __builtin_amdgcn_mfma_f32_32x32x16_bf16(k1, qf[ds], st1, 0, 0, 0);
    }
    __builtin_amdgcn_s_setprio(0);

    // P = exp2(S^T) in native register order (matches permuted V)
    bf16x8 pa[4];
#pragma unroll
    for (int j = 0; j < 8; j++) {
      pa[0][j] = (bf16)exp2f(fminf(st0[j], 86.f));
      pa[1][j] = (bf16)exp2f(fminf(st0[8 + j], 86.f));
      pa[2][j] = (bf16)exp2f(fminf(st1[j], 86.f));
      pa[3][j] = (bf16)exp2f(fminf(st1[8 + j], 86.f));
    }

    // O += P V ; L += P 1
    __builtin_amdgcn_s_setprio(1);
#pragma unroll
    for (int w = 0; w < 4; w++) {
      bf16x8 v0 = *(const bf16x8*)&KB[off[w] + 4096];
      bf16x8 v1 = *(const bf16x8*)&KB[off[w] + 6144];
      accO0 = __builtin_amdgcn_mfma_f32_32x32x16_bf16(pa[w], v0, accO0, 0, 0, 0);
      accO1 = __builtin_amdgcn_mfma_f32_32x32x16_bf16(pa[w], v1, accO1, 0, 0, 0);
      accL  = __builtin_amdgcn_mfma_f32_32x32x16_bf16(pa[w], onesv, accL, 0, 0, 0);
    }
    __builtin_amdgcn_s_setprio(0);

    if (it + 2 < TSEQ / 64)
      asm volatile("s_waitcnt vmcnt(4)" ::: "memory");
    else
      asm volatile("s_waitcnt vmcnt(0)" ::: "memory");
    __builtin_amdgcn_s_barrier();
    asm volatile("" ::: "memory");

    cur = (cur == 2) ? 0 : cur + 1;
    sb  = (sb == 2) ? 0 : sb + 1;
  }

  // epilogue: C row = q = (r&3)+8*(r>>2)+4*l5, col = d = l31 (+32)
#pragma unroll
  for (int r = 0; r < 16; r++) {
    int q = (r & 3) + 8 * (r >> 2) + 4 * l5;
    float rl = 1.0f / fmaxf(accL[r], 1e-30f);
    size_t orow = (bT + q0 + wave * 32 + q) * CDIM + h64;
    O[orow + l31]      = (bf16)(accO0[r] * rl);
    O[orow + 32 + l31] = (bf16)(accO1[r] * rl);
  }
}

// ------------------------------------------------------------------
extern "C" void kernel_launch(void* const* d_in, const int* in_sizes, int n_in,
                              void* d_out, int out_size, void* d_ws, size_t ws_size,
                              hipStream_t stream) {
  char* ws = (char*)d_ws;
  const size_t MB = 1024 * 1024;
  const size_t KB = 1024;

  int* flags = (int*)ws;
  bf16* vec_c = (bf16*)(ws + 4 * KB);
  bf16* ln1g_c = vec_c + 0 * 8192;
  bf16* ln1b_c = vec_c + 1 * 8192;
  bf16* ln2g_c = vec_c + 2 * 8192;
  bf16* ln2b_c = vec_c + 3 * 8192;
  bf16* bqkv_c = vec_c + 4 * 8192;            // [3072]: bq | bk | bv
  bf16* bo_c   = vec_c + 6 * 8192;
  bf16* b1_c   = vec_c + 7 * 8192;
  bf16* b2_c   = vec_c + 8 * 8192;

  bf16*  WqkvT  = (bf16*)(ws + 1 * MB);       // [3072][1024]  1-7   (dead after QKV)
  bf16*  WoT    = (bf16*)(ws + 7 * MB);       // 7-9   (dead after Wo)
  bf16*  W1T    = (bf16*)(ws + 9 * MB);       // 9-17  (dead after FFN1)
  bf16*  W2T    = (bf16*)(ws + 17 * MB);      // 17-25 (live to end)
  bf16*  xn     = (bf16*)(ws + 25 * MB);      // 25-33 (dead after Wo)
  bf16*  QKbuf  = (bf16*)(ws + 33 * MB);      // [4096][2048] 33-49 (dead after attn)
  bf16*  Vtbuf  = (bf16*)(ws + 49 * MB);      // [1024][4096] 49-57 (dead after attn)
  bf16*  ab     = (bf16*)(ws + 57 * MB);      // 57-65 (dead after Wo)
  float* xmid32 = (float*)(ws + 65 * MB);     // 65-81 fp32 (live to end)
  bf16*  h2     = (bf16*)(ws + 81 * MB);      // 81-89 (dead after FFN1)
  bf16*  f1     = (bf16*)(ws + 33 * MB);      // [4096][4096] 33-65 (live to end of W2)
  // W2 split-K partials (8 MB each) -- regions dead at W2 time, disjoint
  // from f1 (33-65) and xmid32 (65-81).
  bf16*  pk0    = (bf16*)(ws + 25 * MB);      // xn region (dead after Wo)
  bf16*  pk1    = (bf16*)(ws + 81 * MB);      // h2 region (dead after FFN1)
  bf16*  pk2    = (bf16*)(ws + 1 * MB);       // WqkvT region (dead after QKV)
  bf16*  pk3    = (bf16*)(ws + 9 * MB);       // W1T region (dead after FFN1)

  // flag idx: 0 x,1 ln1g,2 ln1b,3 ln2g,4 ln2b,5 Wq,6 bq,7 Wk,8 bk,9 Wv,10 bv,
  //           11 Wo,12 bo,13 W1,14 b1,15 W2,16 b2
  const int din_idx[NBUF] = {0, 2, 3, 4, 5, 6, 7, 8, 9, 10, 11, 12, 13, 14, 15, 16, 17};
  DetectArgs da;
  for (int i = 0; i < NBUF; i++) { da.p[i] = d_in[din_idx[i]]; da.n[i] = in_sizes[din_idx[i]]; }
  detect_kernel<<<NBUF, 256, 0, stream>>>(da, flags);

  // ---- mega preprocessing: transposes + vec converts + LN1, one launch ----
  MegaArgs ma;
  {
    const void* wi[6] = {d_in[6], d_in[8], d_in[10], d_in[12], d_in[14], d_in[16]};
    bf16* wo[6] = {WqkvT, WqkvT + 1024 * 1024, WqkvT + 2 * 1024 * 1024, WoT, W1T, W2T};
    const int wK[6] = {1024, 1024, 1024, 1024, 1024, 4096};
    const int wN[6] = {1024, 1024, 1024, 1024, 4096, 1024};
    const int wf[6] = {5, 7, 9, 11, 13, 15};
    for (int i = 0; i < 6; i++) {
      ma.w_in[i] = wi[i]; ma.w_out[i] = wo[i];
      ma.wK[i] = wK[i]; ma.wN[i] = wN[i]; ma.wflag[i] = wf[i];
    }
    const int vf[10] = {1, 2, 3, 4, 6, 8, 10, 12, 14, 16};
    bf16* vd[10] = {ln1g_c, ln1b_c, ln2g_c, ln2b_c,
                    bqkv_c, bqkv_c + 1024, bqkv_c + 2048, bo_c, b1_c, b2_c};
    for (int i = 0; i < 10; i++) {
      int di = din_idx[vf[i]];
      ma.vp[i] = d_in[di]; ma.vd[i] = vd[i]; ma.vn[i] = in_sizes[di]; ma.vfi[i] = vf[i];
    }
    ma.x = d_in[0]; ma.graw = d_in[2]; ma.braw = d_in[3]; ma.y = xn;
  }
  mega_pre<<<3072 + 1 + TOKENS, dim3(64, 4), 0, stream>>>(ma, flags);

  // ---- pipeline ----
  // QKV: M=4096, N=3072, K=1024 -> grid 12x16 = 192 blocks (8-phase 256²)
  gemm256_qkv<<<dim3(12, 16), 512, 0, stream>>>(xn, WqkvT, bqkv_c, QKbuf, Vtbuf);

  attn_kernel<<<512, 256, 0, stream>>>(QKbuf, Vtbuf, ab);

  gemm128<64, 128, EPI_RES, float, bf16><<<dim3(8, 64), 256, 0, stream>>>(
      ab, WoT, bo_c, xn, xmid32, 1024, 1024);

  ln_f32<<<TOKENS, 256, 0, stream>>>(xmid32, ln2g_c, ln2b_c, h2);

  // FFN1: M=4096, N=4096, K=1024 -> grid 16x16 = 256 blocks (8-phase 256²)
  gemm256_gelu<<<dim3(16, 16), 512, 0, stream>>>(h2, W1T, b1_c, f1, 4096, 1024);

  // FFN2 (W2): split-K=4 8-phase 256² (grid 4x16x4 = 256 blocks) + reduce
  gemm256_part<<<dim3(4, 16, 4), 512, 0, stream>>>(f1, W2T, pk0, pk1, pk2, pk3, 4096);
  w2_reduce<<<TOKENS, 256, 0, stream>>>(pk0, pk1, pk2, pk3, xmid32, b2_c, (float*)d_out);
}

// Round 8
// 363.945 us; speedup vs baseline: 1.0238x; 1.0115x over previous
//
#include <hip/hip_runtime.h>
#include <cstdint>
#include <cstddef>

typedef __bf16 bf16;
typedef __bf16 bf16x8 __attribute__((ext_vector_type(8)));
typedef __bf16 bf16x4 __attribute__((ext_vector_type(4)));
typedef float f32x4 __attribute__((ext_vector_type(4)));
typedef float f32x16 __attribute__((ext_vector_type(16)));

#define TOKENS 4096   // B*T
#define TSEQ   2048
#define NHEADS 16
#define HDIM   64
#define CDIM   1024

// ---- async global->LDS, 16B per lane ----
typedef __attribute__((address_space(3))) unsigned int lds_uint;
typedef __attribute__((address_space(1))) const unsigned int g_uint;
__device__ __forceinline__ void glds16(const bf16* g, bf16* l) {
  __builtin_amdgcn_global_load_lds((g_uint*)g, (lds_uint*)l, 16, 0, 0);
}

// fast GELU: x*sigmoid(1.5957691x + 0.0713548x^3); max dev from erf-GELU ~3e-4
__device__ __forceinline__ float gelu_f(float v) {
  float g2 = v * (1.5957691216f + 0.0713548163f * v * v);
  return v / (1.0f + __expf(-g2));
}

// ------------------------------------------------------------------
// Input dtype detection (insurance; fp32 -> flag 0).
// ------------------------------------------------------------------
#define NBUF 17
struct DetectArgs { const void* p[NBUF]; int n[NBUF]; };

__global__ __launch_bounds__(256) void detect_kernel(DetectArgs a, int* __restrict__ flags) {
  __shared__ int s_nz, s_bl;
  if (threadIdx.x == 0) { s_nz = 0; s_bl = 0; }
  __syncthreads();
  int i = blockIdx.x;
  const unsigned int* w = (const unsigned int*)a.p[i];
  int nwords = a.n[i] / 2; if (nwords > 2048) nwords = 2048;
  int nz = 0, bl = 0;
  for (int j = threadIdx.x; j < nwords; j += 256) {
    unsigned int v = w[j];
    if (v != 0u) {
      nz++;
      unsigned int e = (v >> 7) & 0xFFu;
      if (e >= 100u && e <= 140u) bl++;
    }
  }
  atomicAdd(&s_nz, nz);
  atomicAdd(&s_bl, bl);
  __syncthreads();
  if (threadIdx.x == 0) flags[i] = (2 * s_bl >= s_nz) ? 1 : 0;
}

__device__ __forceinline__ float ld_any(const void* p, size_t idx, bool isb) {
  return isb ? (float)((const bf16*)p)[idx] : ((const float*)p)[idx];
}

// ------------------------------------------------------------------
// LayerNorm stats (rows of 1024, 256 threads): returns mu, rstd
// ------------------------------------------------------------------
__device__ __forceinline__ void ln_stats(float s, float s2, int tid, float& mu, float& rstd) {
#pragma unroll
  for (int off = 32; off; off >>= 1) {
    s  += __shfl_down(s, off);
    s2 += __shfl_down(s2, off);
  }
  __shared__ float red[8];
  int w = tid >> 6;
  if ((tid & 63) == 0) { red[w] = s; red[4 + w] = s2; }
  __syncthreads();
  if (tid == 0) {
    red[0] = red[0] + red[1] + red[2] + red[3];
    red[4] = red[4] + red[5] + red[6] + red[7];
  }
  __syncthreads();
  mu = red[0] * (1.0f / CDIM);
  float var = fmaxf(red[4] * (1.0f / CDIM) - mu * mu, 0.f);
  rstd = rsqrtf(var + 1e-5f);
}

__global__ __launch_bounds__(256) void ln_f32(const float* __restrict__ x,
                                              const bf16* __restrict__ g,
                                              const bf16* __restrict__ b,
                                              bf16* __restrict__ y) {
  int row = blockIdx.x, tid = threadIdx.x;
  f32x4 v = *(const f32x4*)&x[(size_t)row * CDIM + tid * 4];
  float s = v[0] + v[1] + v[2] + v[3];
  float s2 = v[0] * v[0] + v[1] * v[1] + v[2] * v[2] + v[3] * v[3];
  float mu, rstd;
  ln_stats(s, s2, tid, mu, rstd);
  bf16x4 gv = *(const bf16x4*)&g[tid * 4];
  bf16x4 bv = *(const bf16x4*)&b[tid * 4];
  bf16x4 o;
#pragma unroll
  for (int i = 0; i < 4; i++)
    o[i] = (bf16)((v[i] - mu) * rstd * (float)gv[i] + (float)bv[i]);
  *(bf16x4*)&y[(size_t)row * CDIM + tid * 4] = o;
}

// ------------------------------------------------------------------
// Mega preprocessing kernel (ONE launch): 6 weight transposes (+convert),
// 10 small-vector converts, LN1 over 4096 rows. Round-7: vectorized
// global loads (f32x4 / bf16x4) and bf16x4 stores (Common-mistake #2).
// ------------------------------------------------------------------
struct MegaArgs {
  const void* w_in[6]; bf16* w_out[6]; int wK[6], wN[6], wflag[6];
  const void* vp[10]; bf16* vd[10]; int vn[10], vfi[10];
  const void* x; const void* graw; const void* braw; bf16* y;
};

__global__ __launch_bounds__(256) void mega_pre(MegaArgs a, const int* __restrict__ flags) {
  int bid = blockIdx.x;
  int tx = threadIdx.x, ty = threadIdx.y;          // blockDim (64,4)
  int tid = tx + ty * 64;
  if (bid < 3072) {
    __shared__ bf16 tile[64][68];                  // 68: rows 136B (8B-aligned)
    int mi, start;
    if (bid < 1024)      { mi = bid >> 8; start = mi << 8; }
    else if (bid < 2048) { mi = 4; start = 1024; }
    else                 { mi = 5; start = 2048; }
    int tb = bid - start;
    int nT = a.wN[mi] >> 6;
    int kb = (tb / nT) * 64, nb = (tb % nT) * 64;
    int K = a.wK[mi], N = a.wN[mi];
    bool isb = flags[a.wflag[mi]] != 0;
    const void* in = a.w_in[mi]; bf16* out = a.w_out[mi];
    int r0 = tid >> 4, c4 = (tid & 15) * 4;
#pragma unroll
    for (int p = 0; p < 4; p++) {
      int r = r0 + p * 16;
      size_t gi = (size_t)(kb + r) * N + nb + c4;
      bf16x4 pk;
      if (isb) {
        pk = *(const bf16x4*)&((const bf16*)in)[gi];
      } else {
        f32x4 f = *(const f32x4*)&((const float*)in)[gi];
#pragma unroll
        for (int j = 0; j < 4; j++) pk[j] = (bf16)f[j];
      }
      *(bf16x4*)&tile[r][c4] = pk;
    }
    __syncthreads();
#pragma unroll
    for (int p = 0; p < 4; p++) {
      int nr = r0 + p * 16;
      bf16x4 o;
#pragma unroll
      for (int j = 0; j < 4; j++) o[j] = tile[c4 + j][nr];
      *(bf16x4*)&out[(size_t)(nb + nr) * K + kb + c4] = o;
    }
  } else if (bid == 3072) {
    for (int i = 0; i < 10; i++) {
      bool isb = flags[a.vfi[i]] != 0;
      const void* in = a.vp[i]; bf16* out = a.vd[i]; int n = a.vn[i];
      for (int j = tid; j < n; j += 256)
        out[j] = (bf16)ld_any(in, j, isb);
    }
  } else {
    int row = bid - 3073;
    bool isb  = flags[0] != 0;
    bool gisb = flags[1] != 0;
    bool bisb = flags[2] != 0;
    float v[4]; float s = 0.f, s2 = 0.f;
    size_t xi = (size_t)row * CDIM + tid * 4;
    if (isb) {
      bf16x4 x4 = *(const bf16x4*)&((const bf16*)a.x)[xi];
#pragma unroll
      for (int i = 0; i < 4; i++) { v[i] = (float)x4[i]; s += v[i]; s2 += v[i] * v[i]; }
    } else {
      f32x4 x4 = *(const f32x4*)&((const float*)a.x)[xi];
#pragma unroll
      for (int i = 0; i < 4; i++) { v[i] = x4[i]; s += v[i]; s2 += v[i] * v[i]; }
    }
    float mu, rstd;
    ln_stats(s, s2, tid, mu, rstd);
    bf16x4 o;
#pragma unroll
    for (int i = 0; i < 4; i++) {
      int c = tid * 4 + i;
      float gv = ld_any(a.graw, c, gisb);
      float bv = ld_any(a.braw, c, bisb);
      o[i] = (bf16)((v[i] - mu) * rstd * gv + bv);
    }
    *(bf16x4*)&a.y[(size_t)row * CDIM + tid * 4] = o;
  }
}

// ------------------------------------------------------------------
// Legacy GEMM core (BM<=128): single-buffer 2-barrier. Kept for Wo.
// ------------------------------------------------------------------
template <int BM, int BN>
__device__ __forceinline__ void gemm_core(const bf16* __restrict__ A,
                                          const bf16* __restrict__ Bt,
                                          int K, int m0, int n0,
                                          bf16* As, bf16* Bs,
                                          f32x4 (&acc)[BM / 32][BN / 32]) {
  constexpr int SI = BM / 32, SJ = BN / 32;
  int t = threadIdx.x;
  int wave = t >> 6, lane = t & 63, quad = lane >> 4, l16 = lane & 15;
  int wm = (wave & 1) * (BM / 2), wn = (wave >> 1) * (BN / 2);
  int srow = t >> 2, sc = t & 3;
  int swz = (srow >> 1) & 3;
  const bf16* ga[BM / 64];
  const bf16* gb[BN / 64];
#pragma unroll
  for (int h = 0; h < BM / 64; h++)
    ga[h] = A + (size_t)(m0 + h * 64 + srow) * K + (sc ^ swz) * 8;
#pragma unroll
  for (int h = 0; h < BN / 64; h++)
    gb[h] = Bt + (size_t)(n0 + h * 64 + srow) * K + (sc ^ swz) * 8;

  for (int k0 = 0; k0 < K; k0 += 64) {
#pragma unroll
    for (int q = 0; q < 2; q++) {
#pragma unroll
      for (int h = 0; h < BM / 64; h++)
        glds16(ga[h] + k0 + q * 32, As + q * (BM * 32) + h * 2048 + srow * 32 + sc * 8);
#pragma unroll
      for (int h = 0; h < BN / 64; h++)
        glds16(gb[h] + k0 + q * 32, Bs + q * (BN * 32) + h * 2048 + srow * 32 + sc * 8);
    }
    __syncthreads();
#pragma unroll
    for (int q = 0; q < 2; q++) {
      bf16x8 af[SI], bfr[SJ];
#pragma unroll
      for (int i = 0; i < SI; i++) {
        int m = wm + i * 16 + l16;
        af[i] = *(const bf16x8*)&As[q * (BM * 32) + m * 32 + ((quad ^ ((m >> 1) & 3)) * 8)];
      }
#pragma unroll
      for (int j = 0; j < SJ; j++) {
        int n = wn + j * 16 + l16;
        bfr[j] = *(const bf16x8*)&Bs[q * (BN * 32) + n * 32 + ((quad ^ ((n >> 1) & 3)) * 8)];
      }
#pragma unroll
      for (int i = 0; i < SI; i++)
#pragma unroll
        for (int j = 0; j < SJ; j++)
          acc[i][j] = __builtin_amdgcn_mfma_f32_16x16x32_bf16(af[i], bfr[j], acc[i][j], 0, 0, 0);
    }
    __syncthreads();
  }
}

#define EPI_NONE 0
#define EPI_RES  1
#define EPI_GELU 2

template <int BM, int BN, int EPI, typename OutT, typename ResT>
__global__ __launch_bounds__(256) void gemm128(const bf16* __restrict__ A,
                                               const bf16* __restrict__ Bt,
                                               const bf16* __restrict__ bias,
                                               const ResT* __restrict__ res,
                                               OutT* __restrict__ C,
                                               int N, int K) {
  __shared__ alignas(16) bf16 As[2 * BM * 32];
  __shared__ alignas(16) bf16 Bs[2 * BN * 32];
  int m0 = blockIdx.y * BM, n0 = blockIdx.x * BN;
  f32x4 acc[BM / 32][BN / 32] = {};
  gemm_core<BM, BN>(A, Bt, K, m0, n0, As, Bs, acc);

  int t = threadIdx.x, wave = t >> 6, lane = t & 63, quad = lane >> 4, l16 = lane & 15;
  int wm = (wave & 1) * (BM / 2), wn = (wave >> 1) * (BN / 2);
#pragma unroll
  for (int i = 0; i < BM / 32; i++)
#pragma unroll
    for (int j = 0; j < BN / 32; j++) {
      int n = n0 + wn + j * 16 + l16;
      float bv = (float)bias[n];
#pragma unroll
      for (int r = 0; r < 4; r++) {
        int m = m0 + wm + i * 16 + quad * 4 + r;
        float v = acc[i][j][r] + bv;
        if (EPI == EPI_GELU)      v = gelu_f(v);
        else if (EPI == EPI_RES)  v += (float)res[(size_t)m * N + n];
        C[(size_t)m * N + n] = (OutT)v;
      }
    }
}

// ------------------------------------------------------------------
// 256x256 8-phase GEMM core (T2+T3+T4+T5): 512 threads = 8 waves (2Mx4N),
// per-wave 128x64 output, BK=64, 128 KiB double-buffered LDS, counted
// vmcnt(6) only at phases 4/8. lda/ldb allow K-sliced operands.
// ------------------------------------------------------------------
__device__ __forceinline__ void gemm256_core(const bf16* __restrict__ A,
                                             const bf16* __restrict__ Bt,
                                             int K, int lda, int ldb, int m0, int n0,
                                             bf16* sm, f32x4 (&acc)[8][4]) {
  const int NT = K >> 6;
  const int t = threadIdx.x;
  const int lane = t & 63, quad = lane >> 4, l16 = lane & 15;
  const int wave = t >> 6;
  const int wm = (wave & 1) * 128, wn = (wave >> 1) * 64;
  const int srow = t >> 2, sc = t & 3;
  const int swz = (srow >> 1) & 3;
  const int rA = (srow & 63) + ((srow >> 6) << 7);   // A-u1 row; u2 = +64
  const bf16* gA = A + (size_t)(m0 + rA) * lda + ((sc ^ swz) << 3);
  const bf16* gB = Bt + (size_t)(n0 + srow) * ldb + ((sc ^ swz) << 3);
  const int ldsA = rA * 32 + sc * 8;
  const int ldsB = srow * 32 + sc * 8;

  auto stA = [&](int tile, int u) {   // u: 0 = rows [0,64)+[128,192), 1 = +64
    if (tile >= NT) return;
    const bf16* g = gA + (size_t)(u << 6) * lda + (tile << 6);
    bf16* l = sm + ((tile & 1) << 15) + ldsA + (u << 11);
    glds16(g, l);
    glds16(g + 32, l + 8192);
  };
  auto stB = [&](int tile, int h) {   // h: 0 = rows [0,128), 1 = [128,256)
    if (tile >= NT) return;
    const bf16* g = gB + (size_t)(h << 7) * ldb + (tile << 6);
    bf16* l = sm + ((tile & 1) << 15) + 16384 + ldsB + (h << 12);
    glds16(g, l);
    glds16(g + 32, l + 8192);
  };

  // prologue: mimic steady-state (j-1)P2..P8, end with vmcnt(6)+barrier
  stB(0, 0); stB(0, 1); stA(0, 0); stA(0, 1);
  stB(1, 0); stB(1, 1); stA(1, 0);
  asm volatile("s_waitcnt vmcnt(6)" ::: "memory");
  __builtin_amdgcn_s_barrier();
  asm volatile("" ::: "memory");

  bf16x8 bfr[2][4];

#define LDB256(buf)                                                        \
  _Pragma("unroll") for (int q = 0; q < 2; q++)                            \
  _Pragma("unroll") for (int j = 0; j < 4; j++) {                          \
    int nl = wn + j * 16 + l16;                                            \
    bfr[q][j] = *(const bf16x8*)&sm[((buf) << 15) + 16384 + q * 8192 +     \
                                    nl * 32 + ((quad ^ ((nl >> 1) & 3)) << 3)]; \
  }

#define PHASE256(buf, P, STAGE, EXTRAWAIT)                                 \
  {                                                                        \
    bf16x8 af[2][2];                                                       \
    _Pragma("unroll") for (int q = 0; q < 2; q++)                          \
    _Pragma("unroll") for (int i2 = 0; i2 < 2; i2++) {                     \
      int ml = wm + (P) * 32 + i2 * 16 + l16;                              \
      af[q][i2] = *(const bf16x8*)&sm[((buf) << 15) + q * 8192 + ml * 32 + \
                                      ((quad ^ ((ml >> 1) & 3)) << 3)];    \
    }                                                                      \
    if ((P) == 0) { LDB256(buf); }                                         \
    STAGE;                                                                 \
    asm volatile("" ::: "memory");                                         \
    __builtin_amdgcn_s_barrier();                                          \
    asm volatile("s_waitcnt lgkmcnt(0)" ::: "memory");                     \
    __builtin_amdgcn_s_setprio(1);                                         \
    _Pragma("unroll") for (int q = 0; q < 2; q++)                          \
    _Pragma("unroll") for (int i2 = 0; i2 < 2; i2++)                       \
    _Pragma("unroll") for (int j = 0; j < 4; j++)                          \
      acc[(P) * 2 + i2][j] = __builtin_amdgcn_mfma_f32_16x16x32_bf16(      \
          af[q][i2], bfr[q][j], acc[(P) * 2 + i2][j], 0, 0, 0);            \
    __builtin_amdgcn_s_setprio(0);                                         \
    asm volatile("" ::: "memory");                                         \
    EXTRAWAIT;                                                             \
    __builtin_amdgcn_s_barrier();                                          \
    asm volatile("" ::: "memory");                                         \
  }

  for (int t0 = 0; t0 < NT; t0 += 2) {
    const int t1 = t0 + 1;
    PHASE256(0, 0, stA(t1, 1), (void)0);
    PHASE256(0, 1, stB(t0 + 2, 0), (void)0);
    PHASE256(0, 2, stB(t0 + 2, 1), (void)0);
    PHASE256(0, 3, stA(t0 + 2, 0),
             asm volatile("s_waitcnt vmcnt(6)" ::: "memory"));
    PHASE256(1, 0, stA(t0 + 2, 1), (void)0);
    PHASE256(1, 1, stB(t1 + 2, 0), (void)0);
    PHASE256(1, 2, stB(t1 + 2, 1), (void)0);
    PHASE256(1, 3, stA(t1 + 2, 0),
             asm volatile("s_waitcnt vmcnt(6)" ::: "memory"));
  }
#undef PHASE256
#undef LDB256
}

__device__ __forceinline__ void xcd_swizzle(int& bx, int& by) {
  int gx = gridDim.x;
  int nwg = gx * gridDim.y;
  int bid = blockIdx.x + blockIdx.y * gx;
  int wg = (bid & 7) * (nwg >> 3) + (bid >> 3);   // nwg % 8 == 0 for our grids
  bx = wg % gx; by = wg / gx;
}

__global__ __launch_bounds__(512, 2) void gemm256_gelu(const bf16* __restrict__ A,
                                                       const bf16* __restrict__ Bt,
                                                       const bf16* __restrict__ bias,
                                                       bf16* __restrict__ C,
                                                       int N, int K) {
  __shared__ alignas(16) bf16 sm[65536];   // 128 KiB
  int bx, by; xcd_swizzle(bx, by);
  int m0 = by * 256, n0 = bx * 256;
  f32x4 acc[8][4] = {};
  gemm256_core(A, Bt, K, K, K, m0, n0, sm, acc);

  int t = threadIdx.x, wave = t >> 6, lane = t & 63, quad = lane >> 4, l16 = lane & 15;
  int wm = (wave & 1) * 128, wn = (wave >> 1) * 64;
#pragma unroll
  for (int i = 0; i < 8; i++)
#pragma unroll
    for (int j = 0; j < 4; j++) {
      int n = n0 + wn + j * 16 + l16;
      float bv = (float)bias[n];
#pragma unroll
      for (int r = 0; r < 4; r++) {
        int m = m0 + wm + i * 16 + quad * 4 + r;
        C[(size_t)m * N + n] = (bf16)gelu_f(acc[i][j][r] + bv);
      }
    }
}

// W2 split-K partial GEMM: grid (4 ntiles, 16 mtiles, 4 kslices); each block
// computes a 256x256 partial over K=1024 and writes bf16 to its slice buffer.
__global__ __launch_bounds__(512, 2) void gemm256_part(const bf16* __restrict__ A,
                                                       const bf16* __restrict__ Bt,
                                                       bf16* __restrict__ P0, bf16* __restrict__ P1,
                                                       bf16* __restrict__ P2, bf16* __restrict__ P3,
                                                       int lda) {
  __shared__ alignas(16) bf16 sm[65536];
  int m0 = blockIdx.y * 256, n0 = blockIdx.x * 256, kz = blockIdx.z;
  const bf16* Ak = A + (size_t)kz * 1024;
  const bf16* Bk = Bt + (size_t)kz * 1024;
  f32x4 acc[8][4] = {};
  gemm256_core(Ak, Bk, 1024, lda, lda, m0, n0, sm, acc);

  bf16* P = (kz == 0) ? P0 : (kz == 1) ? P1 : (kz == 2) ? P2 : P3;
  int t = threadIdx.x, wave = t >> 6, lane = t & 63, quad = lane >> 4, l16 = lane & 15;
  int wm = (wave & 1) * 128, wn = (wave >> 1) * 64;
#pragma unroll
  for (int i = 0; i < 8; i++)
#pragma unroll
    for (int j = 0; j < 4; j++) {
      int n = n0 + wn + j * 16 + l16;
#pragma unroll
      for (int r = 0; r < 4; r++) {
        int m = m0 + wm + i * 16 + quad * 4 + r;
        P[(size_t)m * 1024 + n] = (bf16)acc[i][j][r];
      }
    }
}

// W2 reduce: out = sum(4 partials) + bias + residual (fp32 out).
__global__ __launch_bounds__(256) void w2_reduce(const bf16* __restrict__ P0, const bf16* __restrict__ P1,
                                                 const bf16* __restrict__ P2, const bf16* __restrict__ P3,
                                                 const float* __restrict__ res, const bf16* __restrict__ bias,
                                                 float* __restrict__ out) {
  int c = threadIdx.x * 4;
  size_t base = (size_t)blockIdx.x * 1024 + c;
  bf16x4 a0 = *(const bf16x4*)&P0[base];
  bf16x4 a1 = *(const bf16x4*)&P1[base];
  bf16x4 a2 = *(const bf16x4*)&P2[base];
  bf16x4 a3 = *(const bf16x4*)&P3[base];
  f32x4 rv = *(const f32x4*)&res[base];
  f32x4 o;
#pragma unroll
  for (int i = 0; i < 4; i++)
    o[i] = ((float)a0[i] + (float)a1[i]) + ((float)a2[i] + (float)a3[i]) + rv[i] + (float)bias[c + i];
  *(f32x4*)&out[base] = o;
}

// QKV GEMM (256x256 8-phase). Q cols (n<1024) pre-scaled by 0.125*log2(e)
// (softmax in log2 domain -> native exp2). V cols (n>=2048) written
// transposed AND kv-permuted within 16-token groups (quartets 1<->2), so
// the attn PV B-reads are contiguous b128 matching P's native register
// order (permutation g is an involution; position p holds token g(p)).
__global__ __launch_bounds__(512, 2) void gemm256_qkv(const bf16* __restrict__ A,
                                                      const bf16* __restrict__ Bt,
                                                      const bf16* __restrict__ bias,
                                                      bf16* __restrict__ QK,
                                                      bf16* __restrict__ Vt) {
  __shared__ alignas(16) bf16 sm[65536];
  int bx, by; xcd_swizzle(bx, by);
  int m0 = by * 256, n0 = bx * 256;
  f32x4 acc[8][4] = {};
  gemm256_core(A, Bt, 1024, 1024, 1024, m0, n0, sm, acc);

  int t = threadIdx.x, wave = t >> 6, lane = t & 63, quad = lane >> 4, l16 = lane & 15;
  int wm = (wave & 1) * 128, wn = (wave >> 1) * 64;
#pragma unroll
  for (int i = 0; i < 8; i++)
#pragma unroll
    for (int j = 0; j < 4; j++) {
      int n = n0 + wn + j * 16 + l16;
      float bv = (float)bias[n];
      int mb = m0 + wm + i * 16 + quad * 4;
      if (n < 1024) {
#pragma unroll
        for (int r = 0; r < 4; r++)
          QK[(size_t)(mb + r) * 2048 + n] = (bf16)((acc[i][j][r] + bv) * 0.18033688011112042f);
      } else if (n < 2048) {
#pragma unroll
        for (int r = 0; r < 4; r++)
          QK[(size_t)(mb + r) * 2048 + n] = (bf16)(acc[i][j][r] + bv);
      } else {
        int qt = (mb >> 2) & 3;                       // quartet within 16-group
        int qt2 = ((qt & 1) << 1) | (qt >> 1);        // swap quartets 1<->2
        int mb2 = (mb & ~15) | (qt2 << 2);
        bf16x4 pk;
#pragma unroll
        for (int r = 0; r < 4; r++) pk[r] = (bf16)(acc[i][j][r] + bv);
        *(bf16x4*)&Vt[(size_t)(n - 2048) * TOKENS + mb2] = pk;
      }
    }
}

// ------------------------------------------------------------------
// Flash attention v11 = v8 4-buffer ring + IN-WAVE software pipeline:
// iter it issues QK-MFMA(it), then exp(it-1) on the VALU (overlapping
// the matrix pipe), then PV(it-1). Scores double-buffer in registers
// via hand-unrolled x2 loop (static indexing). V[it-1] stays live one
// iter longer -- the 4-buf ring provides that (WAR: buf (it+2)&3's V
// last read in iter it-1, barrier-separated). vmcnt identical to v8.
// ------------------------------------------------------------------
__global__ __launch_bounds__(256, 2) void attn_kernel(const bf16* __restrict__ QK,
                                                      const bf16* __restrict__ Vt,
                                                      bf16* __restrict__ O) {
  __shared__ alignas(16) bf16 KV[4][8192];   // per buf: K[64][64] @0, V[64][64] @4096
  int bid = blockIdx.x;
  int xcd = bid & 7, slot = bid >> 3;        // XCD-colocate (h,b) groups
  int g = xcd + 8 * (slot >> 4);
  int q0 = (slot & 15) * 128;
  int h = g & 15, b = g >> 4;
  int t = threadIdx.x, wave = t >> 6, lane = t & 63;
  int l31 = lane & 31, l5 = lane >> 5, l7 = lane & 7;

  const bf16* Qg = QK;
  const bf16* Kg = QK + 1024;
  const size_t bT = (size_t)b * TSEQ;
  const int h64 = h * 64;

  int sr = lane >> 3;                 // 0..7
  int sch = l7 ^ sr;                  // pre-swizzled global chunk
  auto stage = [&](int tile, int buf) {
    size_t krow = bT + tile * 64 + wave * 8 + sr;
    bf16* kd = &KV[buf][wave * 512 + lane * 8];
    glds16(&Kg[krow * 2048 + h64 + sch * 8], kd);
    glds16(&Kg[(krow + 32) * 2048 + h64 + sch * 8], kd + 2048);
    size_t vrow = (size_t)(h64 + wave * 8 + sr) * TOKENS + bT + tile * 64 + sch * 8;
    glds16(&Vt[vrow], kd + 4096);
    glds16(&Vt[vrow + (size_t)32 * TOKENS], kd + 6144);
  };

  // Q fragments (B-operand of swapped QK^T): col = q = l31, k = l5*8+j
  bf16x8 qf[4];
  {
    size_t qrow = bT + q0 + wave * 32 + l31;
    const bf16* qp = &Qg[qrow * 2048 + h64 + l5 * 8];
#pragma unroll
    for (int ds = 0; ds < 4; ds++) qf[ds] = *(const bf16x8*)(qp + ds * 16);
  }

  // conflict-free b128 offsets (same form for K and V reads)
  int off[4];
#pragma unroll
  for (int w = 0; w < 4; w++) off[w] = l31 * 64 + (((w * 2 + l5) ^ l7) * 8);

  f32x16 accO0 = {}, accO1 = {}, accL = {};
  const bf16 one = (bf16)1.0f;
  const bf16x8 onesv = {one, one, one, one, one, one, one, one};

  f32x16 sA0, sA1, sB0, sB1;

  stage(0, 0);
  stage(1, 1);
  asm volatile("s_waitcnt vmcnt(4)" ::: "memory");
  __builtin_amdgcn_s_barrier();
  asm volatile("" ::: "memory");

#define QKSTEP(S0, S1, IT)                                                  \
  {                                                                         \
    const bf16* KB = &KV[(IT) & 3][0];                                      \
    S0 = (f32x16){}; S1 = (f32x16){};                                       \
    __builtin_amdgcn_s_setprio(1);                                          \
    _Pragma("unroll") for (int ds = 0; ds < 4; ds++) {                      \
      bf16x8 k0 = *(const bf16x8*)&KB[off[ds]];                             \
      bf16x8 k1 = *(const bf16x8*)&KB[off[ds] + 2048];                      \
      S0 = __builtin_amdgcn_mfma_f32_32x32x16_bf16(k0, qf[ds], S0, 0, 0, 0);\
      S1 = __builtin_amdgcn_mfma_f32_32x32x16_bf16(k1, qf[ds], S1, 0, 0, 0);\
    }                                                                       \
    __builtin_amdgcn_s_setprio(0);                                          \
  }

#define PVSTEP(P0, P1, IT)                                                  \
  {                                                                         \
    bf16x8 pa[4];                                                           \
    _Pragma("unroll") for (int j = 0; j < 8; j++) {                         \
      pa[0][j] = (bf16)exp2f(fminf(P0[j], 86.f));                           \
      pa[1][j] = (bf16)exp2f(fminf(P0[8 + j], 86.f));                       \
      pa[2][j] = (bf16)exp2f(fminf(P1[j], 86.f));                           \
      pa[3][j] = (bf16)exp2f(fminf(P1[8 + j], 86.f));                       \
    }                                                                       \
    const bf16* VB = &KV[(IT) & 3][4096];                                   \
    __builtin_amdgcn_s_setprio(1);                                          \
    _Pragma("unroll") for (int w = 0; w < 4; w++) {                         \
      bf16x8 v0 = *(const bf16x8*)&VB[off[w]];                              \
      bf16x8 v1 = *(const bf16x8*)&VB[off[w] + 2048];                       \
      accO0 = __builtin_amdgcn_mfma_f32_32x32x16_bf16(pa[w], v0, accO0, 0, 0, 0); \
      accO1 = __builtin_amdgcn_mfma_f32_32x32x16_bf16(pa[w], v1, accO1, 0, 0, 0); \
      accL  = __builtin_amdgcn_mfma_f32_32x32x16_bf16(pa[w], onesv, accL, 0, 0, 0); \
    }                                                                       \
    __builtin_amdgcn_s_setprio(0);                                          \
  }

#define ITER(CUR0, CUR1, PRV0, PRV1, IT, DOPV)                              \
  {                                                                         \
    if ((IT) + 2 < TSEQ / 64) stage((IT) + 2, ((IT) + 2) & 3);              \
    QKSTEP(CUR0, CUR1, IT);                                                 \
    if (DOPV) PVSTEP(PRV0, PRV1, (IT) - 1);                                 \
    if ((IT) + 2 < TSEQ / 64)                                               \
      asm volatile("s_waitcnt vmcnt(4)" ::: "memory");                      \
    else                                                                    \
      asm volatile("s_waitcnt vmcnt(0)" ::: "memory");                      \
    __builtin_amdgcn_s_barrier();                                           \
    asm volatile("" ::: "memory");                                          \
  }

  ITER(sA0, sA1, sB0, sB1, 0, false);
  ITER(sB0, sB1, sA0, sA1, 1, true);
  for (int it = 2; it < TSEQ / 64; it += 2) {
    ITER(sA0, sA1, sB0, sB1, it, true);
    ITER(sB0, sB1, sA0, sA1, it + 1, true);
  }
  // epilogue: tile 31's softmax + PV (V[31&3] untouched after loop)
  PVSTEP(sB0, sB1, TSEQ / 64 - 1);

#undef ITER
#undef PVSTEP
#undef QKSTEP

  // epilogue: C row = q = (r&3)+8*(r>>2)+4*l5, col = d = l31 (+32)
#pragma unroll
  for (int r = 0; r < 16; r++) {
    int q = (r & 3) + 8 * (r >> 2) + 4 * l5;
    float rl = 1.0f / fmaxf(accL[r], 1e-30f);
    size_t orow = (bT + q0 + wave * 32 + q) * CDIM + h64;
    O[orow + l31]      = (bf16)(accO0[r] * rl);
    O[orow + 32 + l31] = (bf16)(accO1[r] * rl);
  }
}

// ------------------------------------------------------------------
extern "C" void kernel_launch(void* const* d_in, const int* in_sizes, int n_in,
                              void* d_out, int out_size, void* d_ws, size_t ws_size,
                              hipStream_t stream) {
  char* ws = (char*)d_ws;
  const size_t MB = 1024 * 1024;
  const size_t KB = 1024;

  int* flags = (int*)ws;
  bf16* vec_c = (bf16*)(ws + 4 * KB);
  bf16* ln1g_c = vec_c + 0 * 8192;
  bf16* ln1b_c = vec_c + 1 * 8192;
  bf16* ln2g_c = vec_c + 2 * 8192;
  bf16* ln2b_c = vec_c + 3 * 8192;
  bf16* bqkv_c = vec_c + 4 * 8192;            // [3072]: bq | bk | bv
  bf16* bo_c   = vec_c + 6 * 8192;
  bf16* b1_c   = vec_c + 7 * 8192;
  bf16* b2_c   = vec_c + 8 * 8192;

  bf16*  WqkvT  = (bf16*)(ws + 1 * MB);       // [3072][1024]  1-7   (dead after QKV)
  bf16*  WoT    = (bf16*)(ws + 7 * MB);       // 7-9   (dead after Wo)
  bf16*  W1T    = (bf16*)(ws + 9 * MB);       // 9-17  (dead after FFN1)
  bf16*  W2T    = (bf16*)(ws + 17 * MB);      // 17-25 (live to end)
  bf16*  xn     = (bf16*)(ws + 25 * MB);      // 25-33 (dead after Wo)
  bf16*  QKbuf  = (bf16*)(ws + 33 * MB);      // [4096][2048] 33-49 (dead after attn)
  bf16*  Vtbuf  = (bf16*)(ws + 49 * MB);      // [1024][4096] 49-57 (dead after attn)
  bf16*  ab     = (bf16*)(ws + 57 * MB);      // 57-65 (dead after Wo)
  float* xmid32 = (float*)(ws + 65 * MB);     // 65-81 fp32 (live to end)
  bf16*  h2     = (bf16*)(ws + 81 * MB);      // 81-89 (dead after FFN1)
  bf16*  f1     = (bf16*)(ws + 33 * MB);      // [4096][4096] 33-65 (live to end of W2)
  // W2 split-K partials (8 MB each) -- regions dead at W2 time, disjoint
  // from f1 (33-65) and xmid32 (65-81).
  bf16*  pk0    = (bf16*)(ws + 25 * MB);      // xn region (dead after Wo)
  bf16*  pk1    = (bf16*)(ws + 81 * MB);      // h2 region (dead after FFN1)
  bf16*  pk2    = (bf16*)(ws + 1 * MB);       // WqkvT region (dead after QKV)
  bf16*  pk3    = (bf16*)(ws + 9 * MB);       // W1T region (dead after FFN1)

  // flag idx: 0 x,1 ln1g,2 ln1b,3 ln2g,4 ln2b,5 Wq,6 bq,7 Wk,8 bk,9 Wv,10 bv,
  //           11 Wo,12 bo,13 W1,14 b1,15 W2,16 b2
  const int din_idx[NBUF] = {0, 2, 3, 4, 5, 6, 7, 8, 9, 10, 11, 12, 13, 14, 15, 16, 17};
  DetectArgs da;
  for (int i = 0; i < NBUF; i++) { da.p[i] = d_in[din_idx[i]]; da.n[i] = in_sizes[din_idx[i]]; }
  detect_kernel<<<NBUF, 256, 0, stream>>>(da, flags);

  // ---- mega preprocessing: transposes + vec converts + LN1, one launch ----
  MegaArgs ma;
  {
    const void* wi[6] = {d_in[6], d_in[8], d_in[10], d_in[12], d_in[14], d_in[16]};
    bf16* wo[6] = {WqkvT, WqkvT + 1024 * 1024, WqkvT + 2 * 1024 * 1024, WoT, W1T, W2T};
    const int wK[6] = {1024, 1024, 1024, 1024, 1024, 4096};
    const int wN[6] = {1024, 1024, 1024, 1024, 4096, 1024};
    const int wf[6] = {5, 7, 9, 11, 13, 15};
    for (int i = 0; i < 6; i++) {
      ma.w_in[i] = wi[i]; ma.w_out[i] = wo[i];
      ma.wK[i] = wK[i]; ma.wN[i] = wN[i]; ma.wflag[i] = wf[i];
    }
    const int vf[10] = {1, 2, 3, 4, 6, 8, 10, 12, 14, 16};
    bf16* vd[10] = {ln1g_c, ln1b_c, ln2g_c, ln2b_c,
                    bqkv_c, bqkv_c + 1024, bqkv_c + 2048, bo_c, b1_c, b2_c};
    for (int i = 0; i < 10; i++) {
      int di = din_idx[vf[i]];
      ma.vp[i] = d_in[di]; ma.vd[i] = vd[i]; ma.vn[i] = in_sizes[di]; ma.vfi[i] = vf[i];
    }
    ma.x = d_in[0]; ma.graw = d_in[2]; ma.braw = d_in[3]; ma.y = xn;
  }
  mega_pre<<<3072 + 1 + TOKENS, dim3(64, 4), 0, stream>>>(ma, flags);

  // ---- pipeline ----
  // QKV: M=4096, N=3072, K=1024 -> grid 12x16 = 192 blocks (8-phase 256²)
  gemm256_qkv<<<dim3(12, 16), 512, 0, stream>>>(xn, WqkvT, bqkv_c, QKbuf, Vtbuf);

  attn_kernel<<<512, 256, 0, stream>>>(QKbuf, Vtbuf, ab);

  gemm128<64, 128, EPI_RES, float, bf16><<<dim3(8, 64), 256, 0, stream>>>(
      ab, WoT, bo_c, xn, xmid32, 1024, 1024);

  ln_f32<<<TOKENS, 256, 0, stream>>>(xmid32, ln2g_c, ln2b_c, h2);

  // FFN1: M=4096, N=4096, K=1024 -> grid 16x16 = 256 blocks (8-phase 256²)
  gemm256_gelu<<<dim3(16, 16), 512, 0, stream>>>(h2, W1T, b1_c, f1, 4096, 1024);

  // FFN2 (W2): split-K=4 8-phase 256² (grid 4x16x4 = 256 blocks) + reduce
  gemm256_part<<<dim3(4, 16, 4), 512, 0, stream>>>(f1, W2T, pk0, pk1, pk2, pk3, 4096);
  w2_reduce<<<TOKENS, 256, 0, stream>>>(pk0, pk1, pk2, pk3, xmid32, b2_c, (float*)d_out);
}